// Round 2
// baseline (270.892 us; speedup 1.0000x reference)
//
#include <hip/hip_runtime.h>

#define B_ 2
#define L_ 2048
#define D_ 512
#define H_ 8
#define S_ 2048

typedef __attribute__((ext_vector_type(8))) short short8;
typedef __attribute__((ext_vector_type(8))) unsigned short ushort8;
typedef __attribute__((ext_vector_type(4))) unsigned short ushort4v;
typedef __attribute__((ext_vector_type(4))) float f32x4;
typedef __attribute__((ext_vector_type(16))) float f32x16;
typedef __attribute__((ext_vector_type(4))) float float4v;

__device__ __forceinline__ unsigned short f2bf(float f) {
    unsigned u = __float_as_uint(f);
    u += 0x7FFF + ((u >> 16) & 1);   // RTNE
    return (unsigned short)(u >> 16);
}
__device__ __forceinline__ float bf2f(unsigned short s) {
    return __uint_as_float(((unsigned)s) << 16);
}
// swap bits 2 and 3 (self-inverse) — K-row permutation making S^T C-regs = PV B-frag order
__device__ __forceinline__ int swap23(int x) {
    return (x & ~12) | ((x & 4) << 1) | ((x & 8) >> 1);
}
// async global->LDS, 16B per lane; LDS dest = uniform base + lane*16
__device__ __forceinline__ void async16(void* lds, const void* g) {
    __builtin_amdgcn_global_load_lds(
        (const __attribute__((address_space(1))) void*)(g),
        (__attribute__((address_space(3))) void*)(lds), 16, 0, 0);
}

// ---------------- fused fp32->bf16 converts: x (524288 f4) + 4 weights (65536 f4 each) ----------------
__global__ __launch_bounds__(256) void cvt_all(const float* __restrict__ x,
                                               const float* __restrict__ w0, const float* __restrict__ w1,
                                               const float* __restrict__ w2, const float* __restrict__ w3,
                                               unsigned short* __restrict__ xb,
                                               unsigned short* __restrict__ d0, unsigned short* __restrict__ d1,
                                               unsigned short* __restrict__ d2, unsigned short* __restrict__ d3) {
    int i = blockIdx.x * 256 + threadIdx.x;   // [0, 786432)
    const float* s;
    unsigned short* d;
    int idx;
    if (i < 524288) { s = x; d = xb; idx = i; }
    else {
        int off = i - 524288;                  // [0, 262144): 4 weights x 65536 float4
        int wsel = off >> 16; idx = off & 65535;
        s = (wsel == 0) ? w0 : (wsel == 1) ? w1 : (wsel == 2) ? w2 : w3;
        d = (wsel == 0) ? d0 : (wsel == 1) ? d1 : (wsel == 2) ? d2 : d3;
    }
    float4v v = *(const float4v*)(s + (size_t)idx * 4);
    ushort4v o;
    o[0] = f2bf(v[0]); o[1] = f2bf(v[1]); o[2] = f2bf(v[2]); o[3] = f2bf(v[3]);
    *(ushort4v*)(d + (size_t)idx * 4) = o;
}

// ---------------- content bias (PRE-SCALED by 1/8): cb'[b,h,s] = dot(x,Wb)/8 ----------------
__global__ __launch_bounds__(256) void cb_kernel(const float* __restrict__ x,
                                                 const float* __restrict__ Wb,
                                                 float* __restrict__ cb) {
    const int tid = threadIdx.x, w = tid >> 6, lane = tid & 63;
    const int row = blockIdx.x * 4 + w;            // [0, 4096)
    const int h = lane >> 3, seg = lane & 7;
    const float* xp = x + (size_t)row * 512 + seg * 64;
    const float* wp = Wb + (size_t)h * 512 + seg * 64;
    float acc = 0.f;
    #pragma unroll
    for (int j = 0; j < 16; ++j) {
        float4v xv = *(const float4v*)(xp + j * 4);
        float4v wv = *(const float4v*)(wp + j * 4);
        acc += xv[0] * wv[0] + xv[1] * wv[1] + xv[2] * wv[2] + xv[3] * wv[3];
    }
    acc += __shfl_xor(acc, 1);
    acc += __shfl_xor(acc, 2);
    acc += __shfl_xor(acc, 4);
    if (seg == 0) {
        int b = row >> 11, s = row & 2047;
        cb[((size_t)(b * H_ + h)) * S_ + s] = acc * 0.125f;
    }
}

// ---------------- 128x128-tile GEMM core: 4 waves in 2x2, each 64x64 quadrant ----------------
__device__ __forceinline__ void gemm128_core(const unsigned short* __restrict__ Ap,
                                             const unsigned short* __restrict__ Bp,
                                             short* sA, short* sB, int tid, f32x4 c[4][4]) {
    const int w = tid >> 6, lane = tid & 63, quad = lane >> 4, l15 = lane & 15;
    const int wm = (w >> 1) * 64, wn = (w & 1) * 64;
    for (int kc = 0; kc < 8; ++kc) {
        __syncthreads();
        #pragma unroll
        for (int j = 0; j < 4; ++j) {
            int i = tid + j * 256;          // 1024 slots = 128 rows x 64 cols / 8
            int row = i >> 3, seg = i & 7;
            *(ushort8*)&sA[row * 72 + seg * 8] = *(const ushort8*)(Ap + (size_t)row * 512 + kc * 64 + seg * 8);
            *(ushort8*)&sB[row * 72 + seg * 8] = *(const ushort8*)(Bp + (size_t)row * 512 + kc * 64 + seg * 8);
        }
        __syncthreads();
        #pragma unroll
        for (int ks = 0; ks < 2; ++ks) {
            short8 a[4], b[4];
            #pragma unroll
            for (int ii = 0; ii < 4; ++ii)
                a[ii] = *(const short8*)&sA[(wm + ii * 16 + l15) * 72 + ks * 32 + quad * 8];
            #pragma unroll
            for (int jj = 0; jj < 4; ++jj)
                b[jj] = *(const short8*)&sB[(wn + jj * 16 + l15) * 72 + ks * 32 + quad * 8];
            #pragma unroll
            for (int ii = 0; ii < 4; ++ii)
                #pragma unroll
                for (int jj = 0; jj < 4; ++jj)
                    c[ii][jj] = __builtin_amdgcn_mfma_f32_16x16x32_bf16(a[ii], b[jj], c[ii][jj], 0, 0, 0);
        }
    }
}

// ---------------- q,k,v projections (128x128 tiles) ----------------
// q: row-major bf16.
// K: A-frag packed for 32x32x16, rows sigma-permuted:
//    addr = ((b*64 + (s>>5))*32 + (d>>4))*512 + ((d>>3)&1)*256 + swap23(s&31)*8 + (d&7)
// V: transposed row-major vt[b][h][dh][s]
__global__ __launch_bounds__(256) void gemm_qkv(const unsigned short* __restrict__ xb,
                                                const unsigned short* __restrict__ Wqb,
                                                const unsigned short* __restrict__ Wkb,
                                                const unsigned short* __restrict__ Wvb,
                                                unsigned short* __restrict__ qb,
                                                unsigned short* __restrict__ kpack,
                                                unsigned short* __restrict__ vt) {
    __shared__ short sA[128 * 72];
    __shared__ short sB[128 * 72];
    const int m0 = blockIdx.x * 128, n0 = blockIdx.y * 128, z = blockIdx.z;
    const unsigned short* Bsel = (z == 0) ? Wqb : ((z == 1) ? Wkb : Wvb);
    f32x4 c[4][4];
    #pragma unroll
    for (int ii = 0; ii < 4; ++ii)
        #pragma unroll
        for (int jj = 0; jj < 4; ++jj) { f32x4 zv = {0.f, 0.f, 0.f, 0.f}; c[ii][jj] = zv; }
    gemm128_core(xb + (size_t)m0 * 512, Bsel + (size_t)n0 * 512, sA, sB, threadIdx.x, c);
    const int tid = threadIdx.x, w = tid >> 6, lane = tid & 63, quad = lane >> 4, l15 = lane & 15;
    const int wm = (w >> 1) * 64, wn = (w & 1) * 64;
    #pragma unroll
    for (int ii = 0; ii < 4; ++ii) {
        const int mb = m0 + wm + ii * 16 + quad * 4;
        const int bb = mb >> 11;
        if (z == 0) {
            #pragma unroll
            for (int jj = 0; jj < 4; ++jj) {
                int ncol = n0 + wn + jj * 16 + l15;
                #pragma unroll
                for (int r = 0; r < 4; ++r)
                    qb[(size_t)(mb + r) * 512 + ncol] = f2bf(c[ii][jj][r]);
            }
        } else if (z == 1) {
            #pragma unroll
            for (int jj = 0; jj < 4; ++jj) {
                int d = n0 + wn + jj * 16 + l15;
                int f = d >> 4, hid = (d >> 3) & 1, jq = d & 7;
                #pragma unroll
                for (int r = 0; r < 4; ++r) {
                    int s = (mb + r) & 2047;
                    int t = s >> 5, rr = swap23(s & 31);
                    kpack[(((size_t)(bb * 64 + t)) * 32 + f) * 512 + hid * 256 + rr * 8 + jq]
                        = f2bf(c[ii][jj][r]);
                }
            }
        } else {
            const int hh = (n0 + wn) >> 6;
            const int s = mb & 2047;
            #pragma unroll
            for (int jj = 0; jj < 4; ++jj) {
                int dh = jj * 16 + l15;
                ushort4v o;
                o[0] = f2bf(c[ii][jj][0]); o[1] = f2bf(c[ii][jj][1]);
                o[2] = f2bf(c[ii][jj][2]); o[3] = f2bf(c[ii][jj][3]);
                *(ushort4v*)(vt + (((size_t)(bb * H_ + hh) * 64 + dh) * S_ + s)) = o;
            }
        }
    }
}

// ---------------- output projection (128x128 tiles, fp32 out + bias) ----------------
__global__ __launch_bounds__(256) void gemm_out(const unsigned short* __restrict__ ctxb,
                                                const unsigned short* __restrict__ Wdb,
                                                const float* __restrict__ bd,
                                                float* __restrict__ out) {
    __shared__ short sA[128 * 72];
    __shared__ short sB[128 * 72];
    const int m0 = blockIdx.x * 128, n0 = blockIdx.y * 128;
    f32x4 c[4][4];
    #pragma unroll
    for (int ii = 0; ii < 4; ++ii)
        #pragma unroll
        for (int jj = 0; jj < 4; ++jj) { f32x4 zv = {0.f, 0.f, 0.f, 0.f}; c[ii][jj] = zv; }
    gemm128_core(ctxb + (size_t)m0 * 512, Wdb + (size_t)n0 * 512, sA, sB, threadIdx.x, c);
    const int tid = threadIdx.x, w = tid >> 6, lane = tid & 63, quad = lane >> 4, l15 = lane & 15;
    const int wm = (w >> 1) * 64, wn = (w & 1) * 64;
    #pragma unroll
    for (int ii = 0; ii < 4; ++ii) {
        const int mb = m0 + wm + ii * 16 + quad * 4;
        #pragma unroll
        for (int jj = 0; jj < 4; ++jj) {
            int ncol = n0 + wn + jj * 16 + l15;
            float bias = bd[ncol];
            #pragma unroll
            for (int r = 0; r < 4; ++r)
                out[(size_t)(mb + r) * 512 + ncol] = c[ii][jj][r] + bias;
        }
    }
}

// ---------------- flash attention v11: 64 q-rows/wave (2 q-blocks), K-frag reuse x2 ----------------
// Each ds_read of a K-frag now feeds TWO MFMAs (q-blocks qb=0,1) -> LDS read traffic per unit work
// halved (the measured gate). qf doubles to 256 VGPR -> 1 wave/SIMD (launch_bounds(256,1), 512 budget).
// Grid 256 (1 block/CU): bid = half | b<<1 | h<<2 | qt<<5, qt in [0,8); block = 256 q x 1024 s.
// Staging pipeline + counted-vmcnt FIFO identical to v10 (verified): K chunks 16KB x4 bufs, V x2,
// steady waits vmcnt(9)/(8), tail (5)/(0). Per-wave issue pattern unchanged so counts carry over.
__global__ __launch_bounds__(256, 1) void flash_attn(const unsigned short* __restrict__ qb,
                                                     const unsigned short* __restrict__ kpack,
                                                     const unsigned short* __restrict__ vt,
                                                     const float* __restrict__ cb_all,
                                                     const float* __restrict__ mixing,
                                                     _Float16* __restrict__ Opart,
                                                     float* __restrict__ lpart) {
    __shared__ short sK[4][8192];     // 4 x 16 KB K-chunk buffers (16 A-frags x 512 shorts each)
    __shared__ short sV[2][2048];     // 2 x 4 KB, frag-major (4 frags x 512 shorts)
    const int bid = blockIdx.x;
    const int half = bid & 1, b = (bid >> 1) & 1, h = (bid >> 2) & 7, qt = bid >> 5;
    const int tid = threadIdx.x, w = tid >> 6, lane = tid & 63;
    const int l31 = lane & 31, hi = lane >> 5;
    const int q0 = qt * 256 + w * 64;          // wave owns q0..q0+63 (2 q-blocks of 32)
    const unsigned short* kbase = kpack + ((size_t)(b * 64 + half * 32)) * 32 * 512;
    const unsigned short* vtb = vt + ((size_t)(b * H_ + h) * 64) * (size_t)S_;
    const float* cbp = cb_all + (size_t)(b * H_ + h) * S_ + half * 1024;
    const float* mixh = mixing + h * D_;

    // ---- Q B-frags for both q-blocks (n=q=l31, k=d), mixing folded ----
    short8 qf0[32], qf1[32];
    #pragma unroll
    for (int qb2 = 0; qb2 < 2; ++qb2) {
        const unsigned short* qrow = qb + ((size_t)(b * L_) + q0 + qb2 * 32 + l31) * D_ + hi * 8;
        #pragma unroll
        for (int i = 0; i < 32; ++i) {
            ushort8 qv = *(const ushort8*)(qrow + i * 16);
            float4v ma = *(const float4v*)(mixh + i * 16 + hi * 8);
            float4v mb = *(const float4v*)(mixh + i * 16 + hi * 8 + 4);
            short8 ov;
            ov[0] = (short)f2bf(bf2f(qv[0]) * ma[0]);
            ov[1] = (short)f2bf(bf2f(qv[1]) * ma[1]);
            ov[2] = (short)f2bf(bf2f(qv[2]) * ma[2]);
            ov[3] = (short)f2bf(bf2f(qv[3]) * ma[3]);
            ov[4] = (short)f2bf(bf2f(qv[4]) * mb[0]);
            ov[5] = (short)f2bf(bf2f(qv[5]) * mb[1]);
            ov[6] = (short)f2bf(bf2f(qv[6]) * mb[2]);
            ov[7] = (short)f2bf(bf2f(qv[7]) * mb[3]);
            if (qb2) qf1[i] = ov; else qf0[i] = ov;
        }
    }
    // Drain Q/mixing loads so the hand-counted vmcnt FIFO below starts clean.
    asm volatile("s_waitcnt vmcnt(0)" ::: "memory");

    f32x16 accoA0, accoB0, accoA1, accoB1;     // O^T: [qb][dh-half], 16 f32 each
    #pragma unroll
    for (int i = 0; i < 16; ++i) { accoA0[i] = 0.f; accoB0[i] = 0.f; accoA1[i] = 0.f; accoB1[i] = 0.f; }
    float lsum0 = 0.f, lsum1 = 0.f;
    f32x16 accs0, accs1;                       // S accumulators, one per q-block

    auto stageK = [&](int p) {
        const char* src = (const char*)(kbase + (size_t)p * 8192);
        char* dst = (char*)&sK[p & 3][0];
        #pragma unroll
        for (int ii = 0; ii < 4; ++ii)
            async16(dst + w * 1024 + ii * 4096, src + w * 1024 + ii * 4096 + (size_t)lane * 16);
    };
    // V frag F=w for tile u: dhg=w>>1, sgi=w&1; lane (l31,hi) -> (dh=dhg*32+l31, s=u*32+sgi*16+hi*8)
    auto stageV = [&](int u) {
        const unsigned short* gv = vtb + ((size_t)((w >> 1) * 32 + l31)) * (size_t)S_
                                   + half * 1024 + u * 32 + (w & 1) * 16 + hi * 8;
        async16((char*)&sV[u & 1][0] + w * 1024, gv);
    };
    // One K-frag read feeds both q-blocks: accs0/accs1 alternate -> 2-chain interleave, no bubbles.
    auto qk_chunk = [&](const short* buf, int qbase) {
        __builtin_amdgcn_s_setprio(1);
        #pragma unroll
        for (int f = 0; f < 16; ++f) {
            short8 a = *(const short8*)&buf[f * 512 + lane * 8];
            accs0 = __builtin_amdgcn_mfma_f32_32x32x16_bf16(a, qf0[qbase + f], accs0, 0, 0, 0);
            accs1 = __builtin_amdgcn_mfma_f32_32x32x16_bf16(a, qf1[qbase + f], accs1, 0, 0, 0);
        }
        __builtin_amdgcn_s_setprio(0);
    };
    auto softmax_pv = [&](int t) {
        const int s0 = t * 32;
        float p0[16], p1[16];
        #pragma unroll
        for (int R = 0; R < 16; ++R) {
            const int cr = (R & 3) + 8 * (R >> 2);
            const int idx = s0 + cr - 4 * ((R >> 2) & 1);
            float cbA = cbp[idx];
            float cbB = cbp[idx + 8];
            float cbv = hi ? cbB : cbA;               // shared by both q-blocks (depends on s only)
            float pe0 = __expf(accs0[R] * 0.125f + cbv);
            float pe1 = __expf(accs1[R] * 0.125f + cbv);
            p0[R] = pe0; lsum0 += pe0;
            p1[R] = pe1; lsum1 += pe1;
        }
        // ---- pack P -> bf16 B-frags via +0x8000 (RN) + v_perm, per q-block ----
        union { unsigned int u[4]; short8 s8; } Pa0, Pb0, Pa1, Pb1;
        #pragma unroll
        for (int j = 0; j < 4; ++j) {
            Pa0.u[j] = __builtin_amdgcn_perm(__float_as_uint(p0[2 * j + 1]) + 0x8000u,
                                             __float_as_uint(p0[2 * j]) + 0x8000u, 0x07060302u);
            Pb0.u[j] = __builtin_amdgcn_perm(__float_as_uint(p0[8 + 2 * j + 1]) + 0x8000u,
                                             __float_as_uint(p0[8 + 2 * j]) + 0x8000u, 0x07060302u);
            Pa1.u[j] = __builtin_amdgcn_perm(__float_as_uint(p1[2 * j + 1]) + 0x8000u,
                                             __float_as_uint(p1[2 * j]) + 0x8000u, 0x07060302u);
            Pb1.u[j] = __builtin_amdgcn_perm(__float_as_uint(p1[8 + 2 * j + 1]) + 0x8000u,
                                             __float_as_uint(p1[8 + 2 * j]) + 0x8000u, 0x07060302u);
        }
        // ---- O^T += V^T P^T (V frags shared across q-blocks; 4-gap interleave on acc chains) ----
        {
            short8 av00 = *(const short8*)&sV[t & 1][0 * 512 + lane * 8];
            short8 av01 = *(const short8*)&sV[t & 1][1 * 512 + lane * 8];
            short8 av10 = *(const short8*)&sV[t & 1][2 * 512 + lane * 8];
            short8 av11 = *(const short8*)&sV[t & 1][3 * 512 + lane * 8];
            __builtin_amdgcn_s_setprio(1);
            accoA0 = __builtin_amdgcn_mfma_f32_32x32x16_bf16(av00, Pa0.s8, accoA0, 0, 0, 0);
            accoB0 = __builtin_amdgcn_mfma_f32_32x32x16_bf16(av10, Pa0.s8, accoB0, 0, 0, 0);
            accoA1 = __builtin_amdgcn_mfma_f32_32x32x16_bf16(av00, Pa1.s8, accoA1, 0, 0, 0);
            accoB1 = __builtin_amdgcn_mfma_f32_32x32x16_bf16(av10, Pa1.s8, accoB1, 0, 0, 0);
            accoA0 = __builtin_amdgcn_mfma_f32_32x32x16_bf16(av01, Pb0.s8, accoA0, 0, 0, 0);
            accoB0 = __builtin_amdgcn_mfma_f32_32x32x16_bf16(av11, Pb0.s8, accoB0, 0, 0, 0);
            accoA1 = __builtin_amdgcn_mfma_f32_32x32x16_bf16(av01, Pb1.s8, accoA1, 0, 0, 0);
            accoB1 = __builtin_amdgcn_mfma_f32_32x32x16_bf16(av11, Pb1.s8, accoB1, 0, 0, 0);
            __builtin_amdgcn_s_setprio(0);
        }
    };

    // ---- prologue: mimic phases -3..-1 -> FIFO [K0x4, V0, K1x4, K2x4] = 13 issues ----
    stageK(0); stageV(0); stageK(1); stageK(2);

    for (int t = 0; t < 31; ++t) {
        #pragma unroll
        for (int i = 0; i < 16; ++i) { accs0[i] = 0.f; accs1[i] = 0.f; }
        const short* be = &sK[(t & 1) << 1][0];
        const short* bo = &sK[((t & 1) << 1) | 1][0];
        // ===== even phase p=2t: drain through K(p); leaves V(t), K(p+1)x4, K(p+2)x4 = 9 =====
        asm volatile("s_waitcnt vmcnt(9)" ::: "memory");
        __builtin_amdgcn_s_barrier();
        stageK(2 * t + 3);
        qk_chunk(be, 0);
        // ===== odd phase p=2t+1: drain through K(p) (covers V(t)); leaves K(p+1)x4, K(p+2)x4 = 8 =====
        asm volatile("s_waitcnt vmcnt(8)" ::: "memory");
        __builtin_amdgcn_s_barrier();
        stageV(t + 1);
        if (t < 30) stageK(2 * t + 4);
        qk_chunk(bo, 16);
        softmax_pv(t);
    }
    // ---- t = 31 (phases 62, 63): tail drains ----
    {
        #pragma unroll
        for (int i = 0; i < 16; ++i) { accs0[i] = 0.f; accs1[i] = 0.f; }
        // phase 62: drain through K62; leaves K63x4, V31 = 5
        asm volatile("s_waitcnt vmcnt(5)" ::: "memory");
        __builtin_amdgcn_s_barrier();
        qk_chunk(&sK[2][0], 0);
        // phase 63: drain everything (K63, V31)
        asm volatile("s_waitcnt vmcnt(0)" ::: "memory");
        __builtin_amdgcn_s_barrier();
        qk_chunk(&sK[3][0], 16);
        softmax_pv(31);
    }

    // ---- epilogue: lsum merge, fp16 O^T partials; q position = w*64 + qb*32 + l31 ----
    lsum0 += __shfl_xor(lsum0, 32);
    lsum1 += __shfl_xor(lsum1, 32);
    if (hi == 0) {
        lpart[(size_t)bid * 256 + w * 64 + l31] = lsum0;
        lpart[(size_t)bid * 256 + w * 64 + 32 + l31] = lsum1;
    }
    #pragma unroll
    for (int R = 0; R < 16; ++R) {
        int dh = (R & 3) + 8 * (R >> 2) + 4 * hi;
        Opart[((size_t)bid * 64 + dh) * 256 + w * 64 + l31] = (_Float16)accoA0[R];
        Opart[((size_t)bid * 64 + 32 + dh) * 256 + w * 64 + l31] = (_Float16)accoB0[R];
        Opart[((size_t)bid * 64 + dh) * 256 + w * 64 + 32 + l31] = (_Float16)accoA1[R];
        Opart[((size_t)bid * 64 + 32 + dh) * 256 + w * 64 + 32 + l31] = (_Float16)accoB1[R];
    }
}

// ---------------- merge 2 split-S partials -> ctx (bf16); flash blocks now span 256 q ----------------
__global__ __launch_bounds__(256) void merge_ctx(const _Float16* __restrict__ Opart,
                                                 const float* __restrict__ lpart,
                                                 unsigned short* __restrict__ ctxb) {
    int t = blockIdx.x * 256 + threadIdx.x;       // [0, 524288)
    int qq = t & 255, dh4 = (t >> 8) & 15, qt = (t >> 12) & 7, h = (t >> 15) & 7, b = t >> 18;
    int base = (qt << 5) | (h << 2) | (b << 1);   // flash bid with half=0
    float l = lpart[(size_t)base * 256 + qq] + lpart[(size_t)(base + 1) * 256 + qq];
    float inv = 1.f / l;
    ushort4v o;
    #pragma unroll
    for (int e = 0; e < 4; ++e) {
        int dh = dh4 * 4 + e;
        float v = (float)Opart[((size_t)base * 64 + dh) * 256 + qq]
                + (float)Opart[((size_t)(base + 1) * 64 + dh) * 256 + qq];
        o[e] = f2bf(v * inv);
    }
    *(ushort4v*)(ctxb + ((size_t)(b * L_) + qt * 256 + qq) * 512 + h * 64 + dh4 * 4) = o;
}

extern "C" void kernel_launch(void* const* d_in, const int* in_sizes, int n_in,
                              void* d_out, int out_size, void* d_ws, size_t ws_size,
                              hipStream_t stream) {
    (void)in_sizes; (void)n_in; (void)out_size; (void)ws_size;
    const float* x      = (const float*)d_in[0];
    const float* Wq     = (const float*)d_in[1];
    const float* Wk     = (const float*)d_in[2];
    const float* Wv     = (const float*)d_in[3];
    const float* Wb     = (const float*)d_in[4];
    const float* mixing = (const float*)d_in[5];
    const float* Wd     = (const float*)d_in[6];
    const float* bd     = (const float*)d_in[7];
    float* out = (float*)d_out;

    char* ws = (char*)d_ws;
    const size_t MiB = 1048576;
    unsigned short* xb    = (unsigned short*)(ws);
    unsigned short* qb    = (unsigned short*)(ws + 4 * MiB);
    unsigned short* kpack = (unsigned short*)(ws + 8 * MiB);
    unsigned short* vt    = (unsigned short*)(ws + 12 * MiB);
    unsigned short* ctxb  = (unsigned short*)(ws + 16 * MiB);
    unsigned short* Wqb   = (unsigned short*)(ws + 20 * MiB);
    unsigned short* Wkb   = (unsigned short*)(ws + 20 * MiB + 512 * 1024);
    unsigned short* Wvb   = (unsigned short*)(ws + 21 * MiB);
    unsigned short* Wdb   = (unsigned short*)(ws + 21 * MiB + 512 * 1024);
    float* cbuf           = (float*)(ws + 22 * MiB);            // 128 KB
    float* lpart          = (float*)(ws + 23 * MiB);            // 256 KB
    _Float16* Opart       = (_Float16*)(ws + 24 * MiB);         // 8 MB

    cvt_all<<<3072, 256, 0, stream>>>(x, Wq, Wk, Wv, Wd, xb, Wqb, Wkb, Wvb, Wdb);
    gemm_qkv<<<dim3(32, 4, 3), 256, 0, stream>>>(xb, Wqb, Wkb, Wvb, qb, kpack, vt);
    cb_kernel<<<1024, 256, 0, stream>>>(x, Wb, cbuf);
    flash_attn<<<256, 256, 0, stream>>>(qb, kpack, vt, cbuf, mixing, Opart, lpart);
    merge_ctx<<<2048, 256, 0, stream>>>(Opart, lpart, ctxb);
    gemm_out<<<dim3(32, 4), 256, 0, stream>>>(ctxb, Wdb, bd, out);
}

// Round 3
// 217.560 us; speedup vs baseline: 1.2451x; 1.2451x over previous
//
#include <hip/hip_runtime.h>

#define B_ 2
#define L_ 2048
#define D_ 512
#define H_ 8
#define S_ 2048

typedef __attribute__((ext_vector_type(8))) short short8;
typedef __attribute__((ext_vector_type(8))) unsigned short ushort8;
typedef __attribute__((ext_vector_type(4))) unsigned short ushort4v;
typedef __attribute__((ext_vector_type(4))) float f32x4;
typedef __attribute__((ext_vector_type(16))) float f32x16;
typedef __attribute__((ext_vector_type(4))) float float4v;

__device__ __forceinline__ unsigned short f2bf(float f) {
    unsigned u = __float_as_uint(f);
    u += 0x7FFF + ((u >> 16) & 1);   // RTNE
    return (unsigned short)(u >> 16);
}
__device__ __forceinline__ float bf2f(unsigned short s) {
    return __uint_as_float(((unsigned)s) << 16);
}
// swap bits 2 and 3 (self-inverse) — K-row permutation making S^T C-regs = PV B-frag order
__device__ __forceinline__ int swap23(int x) {
    return (x & ~12) | ((x & 4) << 1) | ((x & 8) >> 1);
}
// async global->LDS, 16B per lane; LDS dest = uniform base + lane*16
__device__ __forceinline__ void async16(void* lds, const void* g) {
    __builtin_amdgcn_global_load_lds(
        (const __attribute__((address_space(1))) void*)(g),
        (__attribute__((address_space(3))) void*)(lds), 16, 0, 0);
}

// ---------------- fused: fp32->bf16 converts (blocks 0..3071) + content bias (blocks 3072..4095) ----------------
// cb PRE-SCALED by 1/8: cb'[b,h,s] = dot(x,Wb)/8
__global__ __launch_bounds__(256) void cvt_cb(const float* __restrict__ x,
                                              const float* __restrict__ w0, const float* __restrict__ w1,
                                              const float* __restrict__ w2, const float* __restrict__ w3,
                                              const float* __restrict__ Wb,
                                              unsigned short* __restrict__ xb,
                                              unsigned short* __restrict__ d0, unsigned short* __restrict__ d1,
                                              unsigned short* __restrict__ d2, unsigned short* __restrict__ d3,
                                              float* __restrict__ cb) {
    if (blockIdx.x < 3072) {
        int i = blockIdx.x * 256 + threadIdx.x;   // [0, 786432)
        const float* s;
        unsigned short* d;
        int idx;
        if (i < 524288) { s = x; d = xb; idx = i; }
        else {
            int off = i - 524288;                  // [0, 262144): 4 weights x 65536 float4
            int wsel = off >> 16; idx = off & 65535;
            s = (wsel == 0) ? w0 : (wsel == 1) ? w1 : (wsel == 2) ? w2 : w3;
            d = (wsel == 0) ? d0 : (wsel == 1) ? d1 : (wsel == 2) ? d2 : d3;
        }
        float4v v = *(const float4v*)(s + (size_t)idx * 4);
        ushort4v o;
        o[0] = f2bf(v[0]); o[1] = f2bf(v[1]); o[2] = f2bf(v[2]); o[3] = f2bf(v[3]);
        *(ushort4v*)(d + (size_t)idx * 4) = o;
    } else {
        const int tid = threadIdx.x, w = tid >> 6, lane = tid & 63;
        const int row = (blockIdx.x - 3072) * 4 + w;   // [0, 4096)
        const int h = lane >> 3, seg = lane & 7;
        const float* xp = x + (size_t)row * 512 + seg * 64;
        const float* wp = Wb + (size_t)h * 512 + seg * 64;
        float acc = 0.f;
        #pragma unroll
        for (int j = 0; j < 16; ++j) {
            float4v xv = *(const float4v*)(xp + j * 4);
            float4v wv = *(const float4v*)(wp + j * 4);
            acc += xv[0] * wv[0] + xv[1] * wv[1] + xv[2] * wv[2] + xv[3] * wv[3];
        }
        acc += __shfl_xor(acc, 1);
        acc += __shfl_xor(acc, 2);
        acc += __shfl_xor(acc, 4);
        if (seg == 0) {
            int b = row >> 11, s = row & 2047;
            cb[((size_t)(b * H_ + h)) * S_ + s] = acc * 0.125f;
        }
    }
}

// ---------------- 128x128-tile GEMM core: 4 waves in 2x2, each 64x64 quadrant ----------------
__device__ __forceinline__ void gemm128_core(const unsigned short* __restrict__ Ap,
                                             const unsigned short* __restrict__ Bp,
                                             short* sA, short* sB, int tid, f32x4 c[4][4]) {
    const int w = tid >> 6, lane = tid & 63, quad = lane >> 4, l15 = lane & 15;
    const int wm = (w >> 1) * 64, wn = (w & 1) * 64;
    for (int kc = 0; kc < 8; ++kc) {
        __syncthreads();
        #pragma unroll
        for (int j = 0; j < 4; ++j) {
            int i = tid + j * 256;          // 1024 slots = 128 rows x 64 cols / 8
            int row = i >> 3, seg = i & 7;
            *(ushort8*)&sA[row * 72 + seg * 8] = *(const ushort8*)(Ap + (size_t)row * 512 + kc * 64 + seg * 8);
            *(ushort8*)&sB[row * 72 + seg * 8] = *(const ushort8*)(Bp + (size_t)row * 512 + kc * 64 + seg * 8);
        }
        __syncthreads();
        #pragma unroll
        for (int ks = 0; ks < 2; ++ks) {
            short8 a[4], b[4];
            #pragma unroll
            for (int ii = 0; ii < 4; ++ii)
                a[ii] = *(const short8*)&sA[(wm + ii * 16 + l15) * 72 + ks * 32 + quad * 8];
            #pragma unroll
            for (int jj = 0; jj < 4; ++jj)
                b[jj] = *(const short8*)&sB[(wn + jj * 16 + l15) * 72 + ks * 32 + quad * 8];
            #pragma unroll
            for (int ii = 0; ii < 4; ++ii)
                #pragma unroll
                for (int jj = 0; jj < 4; ++jj)
                    c[ii][jj] = __builtin_amdgcn_mfma_f32_16x16x32_bf16(a[ii], b[jj], c[ii][jj], 0, 0, 0);
        }
    }
}

// ---------------- q,k,v projections (128x128 tiles) ----------------
// q: row-major bf16.
// K: A-frag packed for 32x32x16, rows sigma-permuted:
//    addr = ((b*64 + (s>>5))*32 + (d>>4))*512 + ((d>>3)&1)*256 + swap23(s&31)*8 + (d&7)
// V: frag-major vfrag[(b,h,T,f)][lane*8] — 1 KB contiguous per (tile,frag), lane l holds
//    (dh=(f>>1)*32+(l&31), s=T*32+(f&1)*16+(l>>5)*8+[0..8)) so flash reads it as one dwordx4/lane.
__global__ __launch_bounds__(256) void gemm_qkv(const unsigned short* __restrict__ xb,
                                                const unsigned short* __restrict__ Wqb,
                                                const unsigned short* __restrict__ Wkb,
                                                const unsigned short* __restrict__ Wvb,
                                                unsigned short* __restrict__ qb,
                                                unsigned short* __restrict__ kpack,
                                                unsigned short* __restrict__ vfrag) {
    __shared__ short sA[128 * 72];
    __shared__ short sB[128 * 72];
    const int m0 = blockIdx.x * 128, n0 = blockIdx.y * 128, z = blockIdx.z;
    const unsigned short* Bsel = (z == 0) ? Wqb : ((z == 1) ? Wkb : Wvb);
    f32x4 c[4][4];
    #pragma unroll
    for (int ii = 0; ii < 4; ++ii)
        #pragma unroll
        for (int jj = 0; jj < 4; ++jj) { f32x4 zv = {0.f, 0.f, 0.f, 0.f}; c[ii][jj] = zv; }
    gemm128_core(xb + (size_t)m0 * 512, Bsel + (size_t)n0 * 512, sA, sB, threadIdx.x, c);
    const int tid = threadIdx.x, w = tid >> 6, lane = tid & 63, quad = lane >> 4, l15 = lane & 15;
    const int wm = (w >> 1) * 64, wn = (w & 1) * 64;
    #pragma unroll
    for (int ii = 0; ii < 4; ++ii) {
        const int mb = m0 + wm + ii * 16 + quad * 4;
        const int bb = mb >> 11;
        if (z == 0) {
            #pragma unroll
            for (int jj = 0; jj < 4; ++jj) {
                int ncol = n0 + wn + jj * 16 + l15;
                #pragma unroll
                for (int r = 0; r < 4; ++r)
                    qb[(size_t)(mb + r) * 512 + ncol] = f2bf(c[ii][jj][r]);
            }
        } else if (z == 1) {
            #pragma unroll
            for (int jj = 0; jj < 4; ++jj) {
                int d = n0 + wn + jj * 16 + l15;
                int f = d >> 4, hid = (d >> 3) & 1, jq = d & 7;
                #pragma unroll
                for (int r = 0; r < 4; ++r) {
                    int s = (mb + r) & 2047;
                    int t = s >> 5, rr = swap23(s & 31);
                    kpack[(((size_t)(bb * 64 + t)) * 32 + f) * 512 + hid * 256 + rr * 8 + jq]
                        = f2bf(c[ii][jj][r]);
                }
            }
        } else {
            const int hh = (n0 + wn) >> 6;
            const int s = mb & 2047;              // s..s+3 along r, s%4==0
            #pragma unroll
            for (int jj = 0; jj < 4; ++jj) {
                int dh = jj * 16 + l15;
                ushort4v o;
                o[0] = f2bf(c[ii][jj][0]); o[1] = f2bf(c[ii][jj][1]);
                o[2] = f2bf(c[ii][jj][2]); o[3] = f2bf(c[ii][jj][3]);
                size_t blk = ((size_t)(bb * H_ + hh) * 64 + (s >> 5)) * 4
                           + ((dh >> 5) * 2 + ((s >> 4) & 1));
                *(ushort4v*)(vfrag + blk * 512 + (dh & 31) * 8 + ((s >> 3) & 1) * 256 + (s & 7)) = o;
            }
        }
    }
}

// ---------------- output projection (128x128 tiles, fp32 out + bias) ----------------
__global__ __launch_bounds__(256) void gemm_out(const unsigned short* __restrict__ ctxb,
                                                const unsigned short* __restrict__ Wdb,
                                                const float* __restrict__ bd,
                                                float* __restrict__ out) {
    __shared__ short sA[128 * 72];
    __shared__ short sB[128 * 72];
    const int m0 = blockIdx.x * 128, n0 = blockIdx.y * 128;
    f32x4 c[4][4];
    #pragma unroll
    for (int ii = 0; ii < 4; ++ii)
        #pragma unroll
        for (int jj = 0; jj < 4; ++jj) { f32x4 zv = {0.f, 0.f, 0.f, 0.f}; c[ii][jj] = zv; }
    gemm128_core(ctxb + (size_t)m0 * 512, Wdb + (size_t)n0 * 512, sA, sB, threadIdx.x, c);
    const int tid = threadIdx.x, w = tid >> 6, lane = tid & 63, quad = lane >> 4, l15 = lane & 15;
    const int wm = (w >> 1) * 64, wn = (w & 1) * 64;
    #pragma unroll
    for (int ii = 0; ii < 4; ++ii) {
        const int mb = m0 + wm + ii * 16 + quad * 4;
        #pragma unroll
        for (int jj = 0; jj < 4; ++jj) {
            int ncol = n0 + wn + jj * 16 + l15;
            float bias = bd[ncol];
            #pragma unroll
            for (int r = 0; r < 4; ++r)
                out[(size_t)(mb + r) * 512 + ncol] = c[ii][jj][r] + bias;
        }
    }
}

// ---------------- flash attention v12: v10 skeleton + V global-direct to regs ----------------
// LDS is the measured gate (v10: 360 KB/CU-step ≈ 106 B/cyc ≈ b128 ceiling). Remove V from LDS
// (-11% LDS bytes): vfrag layout gives 1 coalesced dwordx4/lane per V-frag, L2-resident.
// FIFO per wave (async16 K only, V-reg loads counted): prologue K0,K1,K2 (12).
//   even t: vmcnt(8) [drain K(2t); no-op t>=1]; barrier; ldV(t) [4 loads]; fence; stageK(2t+3); QK chunk0.
//   odd  t: vmcnt(12) [drain K(2t+1)]; barrier; if(t<30) stageK(2t+4); QK chunk1; softmax;
//           vmcnt(8) [drain V(t)+K(2t+2); compiler auto-wait covers t=30/31 tails]; PV.
// v11 lesson: arch-VGPR cap is 256 (spill) and 1 block/CU kills TLP — stay at 128 VGPR, 2 blocks/CU.
__global__ __launch_bounds__(256, 2) void flash_attn(const unsigned short* __restrict__ qb,
                                                     const unsigned short* __restrict__ kpack,
                                                     const unsigned short* __restrict__ vfrag,
                                                     const float* __restrict__ cb_all,
                                                     const float* __restrict__ mixing,
                                                     _Float16* __restrict__ Opart,
                                                     float* __restrict__ lpart) {
    __shared__ short sK[4][8192];     // 4 x 16 KB K-chunk buffers (16 A-frags x 512 shorts each)
    const int bid = blockIdx.x;
    const int half = bid & 1, b = (bid >> 1) & 1, h = (bid >> 2) & 7, qt = bid >> 5;
    const int tid = threadIdx.x, w = tid >> 6, lane = tid & 63;
    const int l31 = lane & 31, hi = lane >> 5;
    const int q0 = qt * 128 + w * 32;
    const unsigned short* kbase = kpack + ((size_t)(b * 64 + half * 32)) * 32 * 512;
    // V frag base for this (b,h): tiles T = half*32 + t, 4 frags x 512 shorts each
    const unsigned short* vfb = vfrag + ((size_t)(b * H_ + h) * 64 + half * 32) * 2048;
    const float* cbp = cb_all + (size_t)(b * H_ + h) * S_ + half * 1024;
    const float* mixh = mixing + h * D_;

    // ---- Q B-frags (n=q=l31, k=d), mixing folded ----
    short8 qf[32];
    {
        const unsigned short* qrow = qb + ((size_t)(b * L_) + q0 + l31) * D_ + hi * 8;
        #pragma unroll
        for (int i = 0; i < 32; ++i) {
            ushort8 qv = *(const ushort8*)(qrow + i * 16);
            float4v ma = *(const float4v*)(mixh + i * 16 + hi * 8);
            float4v mb = *(const float4v*)(mixh + i * 16 + hi * 8 + 4);
            short8 ov;
            ov[0] = (short)f2bf(bf2f(qv[0]) * ma[0]);
            ov[1] = (short)f2bf(bf2f(qv[1]) * ma[1]);
            ov[2] = (short)f2bf(bf2f(qv[2]) * ma[2]);
            ov[3] = (short)f2bf(bf2f(qv[3]) * ma[3]);
            ov[4] = (short)f2bf(bf2f(qv[4]) * mb[0]);
            ov[5] = (short)f2bf(bf2f(qv[5]) * mb[1]);
            ov[6] = (short)f2bf(bf2f(qv[6]) * mb[2]);
            ov[7] = (short)f2bf(bf2f(qv[7]) * mb[3]);
            qf[i] = ov;
        }
    }
    // Drain Q/mixing loads so the hand-counted vmcnt FIFO below starts clean.
    asm volatile("s_waitcnt vmcnt(0)" ::: "memory");

    f32x16 acco0, acco1;
    #pragma unroll
    for (int i = 0; i < 16; ++i) { acco0[i] = 0.f; acco1[i] = 0.f; }
    float lsum = 0.f;
    f32x16 accsA, accsB;
    short8 av00, av01, av10, av11;    // V frags in regs (named: avoid dyn-index scratch, rule #20)

    auto stageK = [&](int p) {
        const char* src = (const char*)(kbase + (size_t)p * 8192);
        char* dst = (char*)&sK[p & 3][0];
        #pragma unroll
        for (int ii = 0; ii < 4; ++ii)
            async16(dst + w * 1024 + ii * 4096, src + w * 1024 + ii * 4096 + (size_t)lane * 16);
    };
    auto ldV = [&](int t) {
        const unsigned short* vp = vfb + (size_t)t * 2048 + lane * 8;
        av00 = *(const short8*)(vp);
        av01 = *(const short8*)(vp + 512);
        av10 = *(const short8*)(vp + 1024);
        av11 = *(const short8*)(vp + 1536);
        asm volatile("" ::: "memory");   // pin the 4 V loads at this FIFO position
    };
    auto qk_chunk = [&](const short* buf, int qbase) {
        __builtin_amdgcn_s_setprio(1);
        #pragma unroll
        for (int f = 0; f < 16; ++f) {
            short8 a = *(const short8*)&buf[f * 512 + lane * 8];
            if (f & 1) accsB = __builtin_amdgcn_mfma_f32_32x32x16_bf16(a, qf[qbase + f], accsB, 0, 0, 0);
            else       accsA = __builtin_amdgcn_mfma_f32_32x32x16_bf16(a, qf[qbase + f], accsA, 0, 0, 0);
        }
        __builtin_amdgcn_s_setprio(0);
    };
    auto softmax_pv = [&](int t) {
        const int s0 = t * 32;
        float p[16];
        #pragma unroll
        for (int R = 0; R < 16; ++R) {
            const int cr = (R & 3) + 8 * (R >> 2);
            const int idx = s0 + cr - 4 * ((R >> 2) & 1);
            float cbA = cbp[idx];
            float cbB = cbp[idx + 8];
            float cbv = hi ? cbB : cbA;
            float pe = __expf((accsA[R] + accsB[R]) * 0.125f + cbv);
            p[R] = pe;
            lsum += pe;
        }
        // ---- pack P -> bf16 B-frags via +0x8000 (RN) + v_perm ----
        union { unsigned int u[4]; short8 s8; } P0, P1;
        #pragma unroll
        for (int j = 0; j < 4; ++j) {
            P0.u[j] = __builtin_amdgcn_perm(__float_as_uint(p[2 * j + 1]) + 0x8000u,
                                            __float_as_uint(p[2 * j]) + 0x8000u, 0x07060302u);
            P1.u[j] = __builtin_amdgcn_perm(__float_as_uint(p[8 + 2 * j + 1]) + 0x8000u,
                                            __float_as_uint(p[8 + 2 * j]) + 0x8000u, 0x07060302u);
        }
        // ---- O^T += V^T P^T (V frags already in regs) ----
        __builtin_amdgcn_s_setprio(1);
        acco0 = __builtin_amdgcn_mfma_f32_32x32x16_bf16(av00, P0.s8, acco0, 0, 0, 0);
        acco0 = __builtin_amdgcn_mfma_f32_32x32x16_bf16(av01, P1.s8, acco0, 0, 0, 0);
        acco1 = __builtin_amdgcn_mfma_f32_32x32x16_bf16(av10, P0.s8, acco1, 0, 0, 0);
        acco1 = __builtin_amdgcn_mfma_f32_32x32x16_bf16(av11, P1.s8, acco1, 0, 0, 0);
        __builtin_amdgcn_s_setprio(0);
    };

    // ---- prologue: 3 K-chunks in flight ----
    stageK(0); stageK(1); stageK(2);

    for (int t = 0; t < 31; ++t) {
        #pragma unroll
        for (int i = 0; i < 16; ++i) { accsA[i] = 0.f; accsB[i] = 0.f; }
        const short* be = &sK[(t & 1) << 1][0];
        const short* bo = &sK[((t & 1) << 1) | 1][0];
        // ===== even phase: K(2t) already drained for t>=1 (by PV wait); t=0 needs the drain =====
        asm volatile("s_waitcnt vmcnt(8)" ::: "memory");
        __builtin_amdgcn_s_barrier();
        ldV(t);
        stageK(2 * t + 3);
        qk_chunk(be, 0);
        // ===== odd phase: drain K(2t+1); leaves [K(2t+2), V(t), K(2t+3)] = 12 =====
        asm volatile("s_waitcnt vmcnt(12)" ::: "memory");
        __builtin_amdgcn_s_barrier();
        if (t < 30) stageK(2 * t + 4);
        qk_chunk(bo, 16);
        // PV: drain V(t) (and K(2t+2)); steady leaves [K(2t+3), K(2t+4)] = 8.
        // t=30 tail: compiler's auto-wait for av covers the deeper drain.
        asm volatile("s_waitcnt vmcnt(8)" ::: "memory");
        softmax_pv(t);
    }
    // ---- t = 31: tail ----
    {
        #pragma unroll
        for (int i = 0; i < 16; ++i) { accsA[i] = 0.f; accsB[i] = 0.f; }
        // even: outstanding [K63]; K62 drained at PV(30)
        asm volatile("s_waitcnt vmcnt(8)" ::: "memory");
        __builtin_amdgcn_s_barrier();
        ldV(31);
        qk_chunk(&sK[2][0], 0);
        // odd: drain K63, leave V31
        asm volatile("s_waitcnt vmcnt(4)" ::: "memory");
        __builtin_amdgcn_s_barrier();
        qk_chunk(&sK[3][0], 16);
        asm volatile("s_waitcnt vmcnt(0)" ::: "memory");
        softmax_pv(31);
    }

    // ---- epilogue: lsum merge, fp16 O^T partials ----
    lsum += __shfl_xor(lsum, 32);
    if (hi == 0) lpart[(size_t)bid * 128 + w * 32 + l31] = lsum;
    #pragma unroll
    for (int R = 0; R < 16; ++R) {
        int dh = (R & 3) + 8 * (R >> 2) + 4 * hi;
        Opart[((size_t)bid * 64 + dh) * 128 + w * 32 + l31] = (_Float16)acco0[R];
        Opart[((size_t)bid * 64 + 32 + dh) * 128 + w * 32 + l31] = (_Float16)acco1[R];
    }
}

// ---------------- merge 2 split-S partials -> ctx (bf16) ----------------
__global__ __launch_bounds__(256) void merge_ctx(const _Float16* __restrict__ Opart,
                                                 const float* __restrict__ lpart,
                                                 unsigned short* __restrict__ ctxb) {
    int t = blockIdx.x * 256 + threadIdx.x;       // [0, 524288)
    int qq = t & 127, dh4 = (t >> 7) & 15, qt = (t >> 11) & 15, h = (t >> 15) & 7, b = t >> 18;
    int base = (qt << 5) | (h << 2) | (b << 1);   // flash bid with half=0
    float l = lpart[(size_t)base * 128 + qq] + lpart[(size_t)(base + 1) * 128 + qq];
    float inv = 1.f / l;
    ushort4v o;
    #pragma unroll
    for (int e = 0; e < 4; ++e) {
        int dh = dh4 * 4 + e;
        float v = (float)Opart[((size_t)base * 64 + dh) * 128 + qq]
                + (float)Opart[((size_t)(base + 1) * 64 + dh) * 128 + qq];
        o[e] = f2bf(v * inv);
    }
    *(ushort4v*)(ctxb + ((size_t)(b * L_) + qt * 128 + qq) * 512 + h * 64 + dh4 * 4) = o;
}

extern "C" void kernel_launch(void* const* d_in, const int* in_sizes, int n_in,
                              void* d_out, int out_size, void* d_ws, size_t ws_size,
                              hipStream_t stream) {
    (void)in_sizes; (void)n_in; (void)out_size; (void)ws_size;
    const float* x      = (const float*)d_in[0];
    const float* Wq     = (const float*)d_in[1];
    const float* Wk     = (const float*)d_in[2];
    const float* Wv     = (const float*)d_in[3];
    const float* Wb     = (const float*)d_in[4];
    const float* mixing = (const float*)d_in[5];
    const float* Wd     = (const float*)d_in[6];
    const float* bd     = (const float*)d_in[7];
    float* out = (float*)d_out;

    char* ws = (char*)d_ws;
    const size_t MiB = 1048576;
    unsigned short* xb    = (unsigned short*)(ws);
    unsigned short* qb    = (unsigned short*)(ws + 4 * MiB);
    unsigned short* kpack = (unsigned short*)(ws + 8 * MiB);
    unsigned short* vfrag = (unsigned short*)(ws + 12 * MiB);
    unsigned short* ctxb  = (unsigned short*)(ws + 16 * MiB);
    unsigned short* Wqb   = (unsigned short*)(ws + 20 * MiB);
    unsigned short* Wkb   = (unsigned short*)(ws + 20 * MiB + 512 * 1024);
    unsigned short* Wvb   = (unsigned short*)(ws + 21 * MiB);
    unsigned short* Wdb   = (unsigned short*)(ws + 21 * MiB + 512 * 1024);
    float* cbuf           = (float*)(ws + 22 * MiB);            // 128 KB
    float* lpart          = (float*)(ws + 23 * MiB);            // 256 KB
    _Float16* Opart       = (_Float16*)(ws + 24 * MiB);         // 8.4 MB

    cvt_cb<<<4096, 256, 0, stream>>>(x, Wq, Wk, Wv, Wd, Wb, xb, Wqb, Wkb, Wvb, Wdb, cbuf);
    gemm_qkv<<<dim3(32, 4, 3), 256, 0, stream>>>(xb, Wqb, Wkb, Wvb, qb, kpack, vfrag);
    flash_attn<<<512, 256, 0, stream>>>(qb, kpack, vfrag, cbuf, mixing, Opart, lpart);
    merge_ctx<<<2048, 256, 0, stream>>>(Opart, lpart, ctxb);
    gemm_out<<<dim3(32, 4), 256, 0, stream>>>(ctxb, Wdb, bd, out);
}

// Round 5
// 200.642 us; speedup vs baseline: 1.3501x; 1.0843x over previous
//
#include <hip/hip_runtime.h>

#define B_ 2
#define L_ 2048
#define D_ 512
#define H_ 8
#define S_ 2048

typedef __attribute__((ext_vector_type(8))) short short8;
typedef __attribute__((ext_vector_type(8))) unsigned short ushort8;
typedef __attribute__((ext_vector_type(4))) unsigned short ushort4v;
typedef __attribute__((ext_vector_type(4))) float f32x4;
typedef __attribute__((ext_vector_type(16))) float f32x16;
typedef __attribute__((ext_vector_type(4))) float float4v;

__device__ __forceinline__ unsigned short f2bf(float f) {
    unsigned u = __float_as_uint(f);
    u += 0x7FFF + ((u >> 16) & 1);   // RTNE
    return (unsigned short)(u >> 16);
}
__device__ __forceinline__ float bf2f(unsigned short s) {
    return __uint_as_float(((unsigned)s) << 16);
}
// f32 -> OCP e4m3 (RTNE, saturating)
__device__ __forceinline__ unsigned char f2fp8(float f) {
    return (unsigned char)(__builtin_amdgcn_cvt_pk_fp8_f32(f, f, 0, false) & 0xff);
}
// pack 8 f32 -> 8 e4m3 bytes in one i64 (byte j = v[j])
__device__ __forceinline__ long pack8fp8(const float* v) {
    int lo = __builtin_amdgcn_cvt_pk_fp8_f32(v[0], v[1], 0, false);
    lo = __builtin_amdgcn_cvt_pk_fp8_f32(v[2], v[3], lo, true);
    int hi = __builtin_amdgcn_cvt_pk_fp8_f32(v[4], v[5], 0, false);
    hi = __builtin_amdgcn_cvt_pk_fp8_f32(v[6], v[7], hi, true);
    union { int i[2]; long l; } u;
    u.i[0] = lo; u.i[1] = hi;
    return u.l;
}
// swap bits 2 and 3 (self-inverse) — K-row permutation making S^T C-regs = PV B-frag order
__device__ __forceinline__ int swap23(int x) {
    return (x & ~12) | ((x & 4) << 1) | ((x & 8) >> 1);
}
// async global->LDS, 16B per lane; LDS dest = uniform base + lane*16
__device__ __forceinline__ void async16(void* lds, const void* g) {
    __builtin_amdgcn_global_load_lds(
        (const __attribute__((address_space(1))) void*)(g),
        (__attribute__((address_space(3))) void*)(lds), 16, 0, 0);
}

// ---------------- fused: fp32->bf16 converts (blocks 0..3071) + content bias (blocks 3072..4095) ----------------
// cb PRE-SCALED by 1/8 and stored bf16: cb'[b,h,s] = dot(x,Wb)/8
__global__ __launch_bounds__(256) void cvt_cb(const float* __restrict__ x,
                                              const float* __restrict__ w0, const float* __restrict__ w1,
                                              const float* __restrict__ w2, const float* __restrict__ w3,
                                              const float* __restrict__ Wb,
                                              unsigned short* __restrict__ xb,
                                              unsigned short* __restrict__ d0, unsigned short* __restrict__ d1,
                                              unsigned short* __restrict__ d2, unsigned short* __restrict__ d3,
                                              unsigned short* __restrict__ cb) {
    if (blockIdx.x < 3072) {
        int i = blockIdx.x * 256 + threadIdx.x;   // [0, 786432)
        const float* s;
        unsigned short* d;
        int idx;
        if (i < 524288) { s = x; d = xb; idx = i; }
        else {
            int off = i - 524288;                  // [0, 262144): 4 weights x 65536 float4
            int wsel = off >> 16; idx = off & 65535;
            s = (wsel == 0) ? w0 : (wsel == 1) ? w1 : (wsel == 2) ? w2 : w3;
            d = (wsel == 0) ? d0 : (wsel == 1) ? d1 : (wsel == 2) ? d2 : d3;
        }
        float4v v = *(const float4v*)(s + (size_t)idx * 4);
        ushort4v o;
        o[0] = f2bf(v[0]); o[1] = f2bf(v[1]); o[2] = f2bf(v[2]); o[3] = f2bf(v[3]);
        *(ushort4v*)(d + (size_t)idx * 4) = o;
    } else {
        const int tid = threadIdx.x, w = tid >> 6, lane = tid & 63;
        const int row = (blockIdx.x - 3072) * 4 + w;   // [0, 4096)
        const int h = lane >> 3, seg = lane & 7;
        const float* xp = x + (size_t)row * 512 + seg * 64;
        const float* wp = Wb + (size_t)h * 512 + seg * 64;
        float acc = 0.f;
        #pragma unroll
        for (int j = 0; j < 16; ++j) {
            float4v xv = *(const float4v*)(xp + j * 4);
            float4v wv = *(const float4v*)(wp + j * 4);
            acc += xv[0] * wv[0] + xv[1] * wv[1] + xv[2] * wv[2] + xv[3] * wv[3];
        }
        acc += __shfl_xor(acc, 1);
        acc += __shfl_xor(acc, 2);
        acc += __shfl_xor(acc, 4);
        if (seg == 0) {
            int b = row >> 11, s = row & 2047;
            cb[((size_t)(b * H_ + h)) * S_ + s] = f2bf(acc * 0.125f);
        }
    }
}

// ---------------- 128x128-tile GEMM core: 4 waves in 2x2, each 64x64 quadrant ----------------
__device__ __forceinline__ void gemm128_core(const unsigned short* __restrict__ Ap,
                                             const unsigned short* __restrict__ Bp,
                                             short* sA, short* sB, int tid, f32x4 c[4][4]) {
    const int w = tid >> 6, lane = tid & 63, quad = lane >> 4, l15 = lane & 15;
    const int wm = (w >> 1) * 64, wn = (w & 1) * 64;
    for (int kc = 0; kc < 8; ++kc) {
        __syncthreads();
        #pragma unroll
        for (int j = 0; j < 4; ++j) {
            int i = tid + j * 256;          // 1024 slots = 128 rows x 64 cols / 8
            int row = i >> 3, seg = i & 7;
            *(ushort8*)&sA[row * 72 + seg * 8] = *(const ushort8*)(Ap + (size_t)row * 512 + kc * 64 + seg * 8);
            *(ushort8*)&sB[row * 72 + seg * 8] = *(const ushort8*)(Bp + (size_t)row * 512 + kc * 64 + seg * 8);
        }
        __syncthreads();
        #pragma unroll
        for (int ks = 0; ks < 2; ++ks) {
            short8 a[4], b[4];
            #pragma unroll
            for (int ii = 0; ii < 4; ++ii)
                a[ii] = *(const short8*)&sA[(wm + ii * 16 + l15) * 72 + ks * 32 + quad * 8];
            #pragma unroll
            for (int jj = 0; jj < 4; ++jj)
                b[jj] = *(const short8*)&sB[(wn + jj * 16 + l15) * 72 + ks * 32 + quad * 8];
            #pragma unroll
            for (int ii = 0; ii < 4; ++ii)
                #pragma unroll
                for (int jj = 0; jj < 4; ++jj)
                    c[ii][jj] = __builtin_amdgcn_mfma_f32_16x16x32_bf16(a[ii], b[jj], c[ii][jj], 0, 0, 0);
        }
    }
}

// ---------------- q,k,v projections (128x128 tiles) ----------------
// q: row-major bf16 (flash folds mixing + quantizes per-head in-register).
// K: fp8 e4m3 (x32, NO mixing) A-frag pair-packed, rows sigma-permuted:
//    byte = ((b*64 + (s>>5))*16 + (d>>5))*1024 + (((d>>3)&1)*32 + swap23(s&31))*16 + ((d>>4)&1)*8 + (d&7)
// V: frag-major vfrag[(b,h,T,f)][lane*8] — flash reads one dwordx4/lane.
__global__ __launch_bounds__(256) void gemm_qkv(const unsigned short* __restrict__ xb,
                                                const unsigned short* __restrict__ Wqb,
                                                const unsigned short* __restrict__ Wkb,
                                                const unsigned short* __restrict__ Wvb,
                                                unsigned short* __restrict__ qb,
                                                unsigned char* __restrict__ kpack8,
                                                unsigned short* __restrict__ vfrag) {
    __shared__ short sA[128 * 72];
    __shared__ short sB[128 * 72];
    const int m0 = blockIdx.x * 128, n0 = blockIdx.y * 128, z = blockIdx.z;
    const unsigned short* Bsel = (z == 0) ? Wqb : ((z == 1) ? Wkb : Wvb);
    f32x4 c[4][4];
    #pragma unroll
    for (int ii = 0; ii < 4; ++ii)
        #pragma unroll
        for (int jj = 0; jj < 4; ++jj) { f32x4 zv = {0.f, 0.f, 0.f, 0.f}; c[ii][jj] = zv; }
    gemm128_core(xb + (size_t)m0 * 512, Bsel + (size_t)n0 * 512, sA, sB, threadIdx.x, c);
    const int tid = threadIdx.x, w = tid >> 6, lane = tid & 63, quad = lane >> 4, l15 = lane & 15;
    const int wm = (w >> 1) * 64, wn = (w & 1) * 64;
    #pragma unroll
    for (int ii = 0; ii < 4; ++ii) {
        const int mb = m0 + wm + ii * 16 + quad * 4;
        const int bb = mb >> 11;
        if (z == 0) {
            #pragma unroll
            for (int jj = 0; jj < 4; ++jj) {
                int ncol = n0 + wn + jj * 16 + l15;
                #pragma unroll
                for (int r = 0; r < 4; ++r)
                    qb[(size_t)(mb + r) * 512 + ncol] = f2bf(c[ii][jj][r]);
            }
        } else if (z == 1) {
            #pragma unroll
            for (int jj = 0; jj < 4; ++jj) {
                int d = n0 + wn + jj * 16 + l15;
                int pair = d >> 5, fh = (d >> 4) & 1, hid = (d >> 3) & 1, jq = d & 7;
                #pragma unroll
                for (int r = 0; r < 4; ++r) {
                    int s = (mb + r) & 2047;
                    int t = s >> 5, rr = swap23(s & 31);
                    kpack8[(((size_t)(bb * 64 + t) * 16 + pair) << 10)
                           + (hid * 32 + rr) * 16 + fh * 8 + jq] = f2fp8(c[ii][jj][r] * 32.f);
                }
            }
        } else {
            const int hh = (n0 + wn) >> 6;
            const int s = mb & 2047;              // s..s+3 along r, s%4==0
            #pragma unroll
            for (int jj = 0; jj < 4; ++jj) {
                int dh = jj * 16 + l15;
                ushort4v o;
                o[0] = f2bf(c[ii][jj][0]); o[1] = f2bf(c[ii][jj][1]);
                o[2] = f2bf(c[ii][jj][2]); o[3] = f2bf(c[ii][jj][3]);
                size_t blk = ((size_t)(bb * H_ + hh) * 64 + (s >> 5)) * 4
                           + ((dh >> 5) * 2 + ((s >> 4) & 1));
                *(ushort4v*)(vfrag + blk * 512 + (dh & 31) * 8 + ((s >> 3) & 1) * 256 + (s & 7)) = o;
            }
        }
    }
}

// ---------------- output projection (128x128 tiles, fp32 out + bias) ----------------
__global__ __launch_bounds__(256) void gemm_out(const unsigned short* __restrict__ ctxb,
                                                const unsigned short* __restrict__ Wdb,
                                                const float* __restrict__ bd,
                                                float* __restrict__ out) {
    __shared__ short sA[128 * 72];
    __shared__ short sB[128 * 72];
    const int m0 = blockIdx.x * 128, n0 = blockIdx.y * 128;
    f32x4 c[4][4];
    #pragma unroll
    for (int ii = 0; ii < 4; ++ii)
        #pragma unroll
        for (int jj = 0; jj < 4; ++jj) { f32x4 zv = {0.f, 0.f, 0.f, 0.f}; c[ii][jj] = zv; }
    gemm128_core(ctxb + (size_t)m0 * 512, Wdb + (size_t)n0 * 512, sA, sB, threadIdx.x, c);
    const int tid = threadIdx.x, w = tid >> 6, lane = tid & 63, quad = lane >> 4, l15 = lane & 15;
    const int wm = (w >> 1) * 64, wn = (w & 1) * 64;
    #pragma unroll
    for (int ii = 0; ii < 4; ++ii) {
        const int mb = m0 + wm + ii * 16 + quad * 4;
        #pragma unroll
        for (int jj = 0; jj < 4; ++jj) {
            int ncol = n0 + wn + jj * 16 + l15;
            float bias = bd[ncol];
            #pragma unroll
            for (int r = 0; r < 4; ++r)
                out[(size_t)(mb + r) * 512 + ncol] = c[ii][jj][r] + bias;
        }
    }
}

// ---------------- flash attention v14: fp8 QK (mixing folded into Q in-register), cb in regs ----------------
// K chunks 8 KB fp8 (one ds_read_b128 feeds 2 MFMAs). Q quantized to fp8 B-frags in the prologue
// (per-head mixing at f32, then cvt_pk_fp8). kpack8 is head-independent (2 MB, L2-resident).
// FIFO per wave (stageK=2, ldV=4, ldCB=4): prologue K0,K1,K2 (6).
//   even t: vmcnt(4) [K(2t); no-op t>=1]; barrier; ldV(t); ldCB(t); stageK(2t+3); QK chunk0.
//   odd  t: vmcnt(12) [K(2t+1)]; barrier; stageK(2t+4) (t<30); QK chunk1; softmax (compiler emits
//           vmcnt(4) for cb regs -> drains V+cb, PRESERVES K(2t+3),K(2t+4) in flight); PV.
// Peeled t=31: even vmcnt(4)/odd vmcnt(8)/implicit 0. Logit scale: q*16, k*32, /8 head -> accs/4096.
__global__ __launch_bounds__(256, 2) void flash_attn(const unsigned short* __restrict__ qb,
                                                     const unsigned char* __restrict__ kpack8,
                                                     const unsigned short* __restrict__ vfrag,
                                                     const unsigned short* __restrict__ cb_all,
                                                     const float* __restrict__ mixing,
                                                     _Float16* __restrict__ Opart,
                                                     float* __restrict__ lpart) {
    __shared__ char sK[4][8192];     // 4 x 8 KB fp8 K-chunk buffers (8 frag-pairs x 1024 B each)
    const int bid = blockIdx.x;
    const int half = bid & 1, b = (bid >> 1) & 1, h = (bid >> 2) & 7, qt = bid >> 5;
    const int tid = threadIdx.x, w = tid >> 6, lane = tid & 63;
    const int l31 = lane & 31, hi = lane >> 5;
    const int q0 = qt * 128 + w * 32;
    const unsigned char* kbase = kpack8 + (((size_t)(b * 64 + half * 32)) << 14);
    const unsigned short* vfb = vfrag + ((size_t)(b * H_ + h) * 64 + half * 32) * 2048;
    const unsigned short* cbq = cb_all + (size_t)(b * H_ + h) * S_ + half * 1024;
    const float* mixh = mixing + h * D_;

    // ---- Q: bf16 rows -> x mixing (f32) -> fp8 B-frags in regs (frag i: d = i*16 + hi*8 + j) ----
    long qq[32];
    {
        const unsigned short* qrow = qb + ((size_t)(b * L_) + q0 + l31) * D_ + hi * 8;
        #pragma unroll
        for (int i = 0; i < 32; ++i) {
            ushort8 qv = *(const ushort8*)(qrow + i * 16);
            float4v ma = *(const float4v*)(mixh + i * 16 + hi * 8);
            float4v mb = *(const float4v*)(mixh + i * 16 + hi * 8 + 4);
            float v[8];
            v[0] = bf2f(qv[0]) * ma[0] * 16.f;
            v[1] = bf2f(qv[1]) * ma[1] * 16.f;
            v[2] = bf2f(qv[2]) * ma[2] * 16.f;
            v[3] = bf2f(qv[3]) * ma[3] * 16.f;
            v[4] = bf2f(qv[4]) * mb[0] * 16.f;
            v[5] = bf2f(qv[5]) * mb[1] * 16.f;
            v[6] = bf2f(qv[6]) * mb[2] * 16.f;
            v[7] = bf2f(qv[7]) * mb[3] * 16.f;
            qq[i] = pack8fp8(v);
        }
    }
    // Drain Q/mixing loads so the hand-counted vmcnt FIFO below starts clean.
    asm volatile("s_waitcnt vmcnt(0)" ::: "memory");

    f32x16 acco0, acco1;
    #pragma unroll
    for (int i = 0; i < 16; ++i) { acco0[i] = 0.f; acco1[i] = 0.f; }
    float lsum = 0.f;
    f32x16 accsA, accsB;
    short8 av00, av01, av10, av11;       // V frags (bf16) in regs
    ushort8 cbr0, cbr1, cbr2, cbr3;      // cb tile (bf16) in regs

    auto stageK = [&](int p) {
        const char* src = (const char*)kpack8 + (((size_t)(b * 64 + half * 32)) << 14) + (size_t)p * 8192;
        char* dst = &sK[p & 3][0];
        #pragma unroll
        for (int ii = 0; ii < 2; ++ii)
            async16(dst + w * 1024 + ii * 4096, src + w * 1024 + ii * 4096 + (size_t)lane * 16);
    };
    auto ldV = [&](int t) {
        const unsigned short* vp = vfb + (size_t)t * 2048 + lane * 8;
        av00 = *(const short8*)(vp);
        av01 = *(const short8*)(vp + 512);
        av10 = *(const short8*)(vp + 1024);
        av11 = *(const short8*)(vp + 1536);
        asm volatile("" ::: "memory");   // pin the 4 V loads at this FIFO position
    };
    auto ldCB = [&](int t) {
        const unsigned short* cp = cbq + t * 32;
        cbr0 = *(const ushort8*)(cp);
        cbr1 = *(const ushort8*)(cp + 8);
        cbr2 = *(const ushort8*)(cp + 16);
        cbr3 = *(const ushort8*)(cp + 24);
        asm volatile("" ::: "memory");   // pin the 4 cb loads at this FIFO position
    };
    auto qk_chunk = [&](const char* buf, int qbase) {   // qbase = 0 or 16 (frag base)
        __builtin_amdgcn_s_setprio(1);
        #pragma unroll
        for (int p = 0; p < 8; ++p) {
            long a0, a1;
            {
                const long* ap = (const long*)&buf[p * 1024 + lane * 16];
                a0 = ap[0];
                a1 = ap[1];
            }
            accsA = __builtin_amdgcn_mfma_f32_32x32x16_fp8_fp8(a0, qq[qbase + 2 * p], accsA, 0, 0, 0);
            accsB = __builtin_amdgcn_mfma_f32_32x32x16_fp8_fp8(a1, qq[qbase + 2 * p + 1], accsB, 0, 0, 0);
        }
        __builtin_amdgcn_s_setprio(0);
    };
    auto softmax_pv = [&]() {
        float p[16];
        #pragma unroll
        for (int R = 0; R < 16; ++R) {
            const int cr = (R & 3) + 8 * (R >> 2);
            const int il = cr - 4 * ((R >> 2) & 1);    // in [0..7] u [16..23]
            const int ih = il + 8;                      // in [8..15] u [24..31]
            unsigned short ca = (il < 8)  ? cbr0[il & 7] : cbr2[il & 7];
            unsigned short cbb = (ih < 16) ? cbr1[ih & 7] : cbr3[ih & 7];
            float cbv = bf2f(hi ? cbb : ca);
            float pe = __expf((accsA[R] + accsB[R]) * (1.0f / 4096.0f) + cbv);
            p[R] = pe;
            lsum += pe;
        }
        // ---- pack P -> bf16 B-frags via +0x8000 (RN) + v_perm ----
        union { unsigned int u[4]; short8 s8; } P0, P1;
        #pragma unroll
        for (int j = 0; j < 4; ++j) {
            P0.u[j] = __builtin_amdgcn_perm(__float_as_uint(p[2 * j + 1]) + 0x8000u,
                                            __float_as_uint(p[2 * j]) + 0x8000u, 0x07060302u);
            P1.u[j] = __builtin_amdgcn_perm(__float_as_uint(p[8 + 2 * j + 1]) + 0x8000u,
                                            __float_as_uint(p[8 + 2 * j]) + 0x8000u, 0x07060302u);
        }
        // ---- O^T += V^T P^T (V frags already in regs) ----
        __builtin_amdgcn_s_setprio(1);
        acco0 = __builtin_amdgcn_mfma_f32_32x32x16_bf16(av00, P0.s8, acco0, 0, 0, 0);
        acco0 = __builtin_amdgcn_mfma_f32_32x32x16_bf16(av01, P1.s8, acco0, 0, 0, 0);
        acco1 = __builtin_amdgcn_mfma_f32_32x32x16_bf16(av10, P0.s8, acco1, 0, 0, 0);
        acco1 = __builtin_amdgcn_mfma_f32_32x32x16_bf16(av11, P1.s8, acco1, 0, 0, 0);
        __builtin_amdgcn_s_setprio(0);
    };

    // ---- prologue: 3 K-chunks in flight (6 loads) ----
    stageK(0); stageK(1); stageK(2);

    for (int t = 0; t < 31; ++t) {
        #pragma unroll
        for (int i = 0; i < 16; ++i) { accsA[i] = 0.f; accsB[i] = 0.f; }
        const char* be = &sK[(t & 1) << 1][0];
        const char* bo = &sK[((t & 1) << 1) | 1][0];
        // ===== even phase: drain K(2t) (t=0 real; no-op t>=1) =====
        asm volatile("s_waitcnt vmcnt(4)" ::: "memory");
        __builtin_amdgcn_s_barrier();
        ldV(t);
        ldCB(t);
        stageK(2 * t + 3);
        qk_chunk(be, 0);
        // ===== odd phase: drain K(2t+1); leaves [K(2t+2), V, cb, K(2t+3)] = 12 =====
        asm volatile("s_waitcnt vmcnt(12)" ::: "memory");
        __builtin_amdgcn_s_barrier();
        if (t < 30) stageK(2 * t + 4);
        qk_chunk(bo, 16);
        // softmax's cb use -> compiler vmcnt(4): drains V+cb (and K(2t+2)),
        // keeps K(2t+3),K(2t+4) in flight.
        softmax_pv();
    }
    // ---- t = 31 (peeled): chunks 62,63 in sK[2],sK[3] ----
    {
        #pragma unroll
        for (int i = 0; i < 16; ++i) { accsA[i] = 0.f; accsB[i] = 0.f; }
        asm volatile("s_waitcnt vmcnt(4)" ::: "memory");   // no-op (K62 drained at softmax(30))
        __builtin_amdgcn_s_barrier();
        ldV(31);
        ldCB(31);
        qk_chunk(&sK[2][0], 0);
        asm volatile("s_waitcnt vmcnt(8)" ::: "memory");   // drain K63; leave V31+cb31
        __builtin_amdgcn_s_barrier();
        qk_chunk(&sK[3][0], 16);
        softmax_pv();                                       // compiler drains V/cb
    }

    // ---- epilogue: lsum merge, fp16 O^T partials ----
    lsum += __shfl_xor(lsum, 32);
    if (hi == 0) lpart[(size_t)bid * 128 + w * 32 + l31] = lsum;
    #pragma unroll
    for (int R = 0; R < 16; ++R) {
        int dh = (R & 3) + 8 * (R >> 2) + 4 * hi;
        Opart[((size_t)bid * 64 + dh) * 128 + w * 32 + l31] = (_Float16)acco0[R];
        Opart[((size_t)bid * 64 + 32 + dh) * 128 + w * 32 + l31] = (_Float16)acco1[R];
    }
}

// ---------------- merge 2 split-S partials -> ctx (bf16) ----------------
__global__ __launch_bounds__(256) void merge_ctx(const _Float16* __restrict__ Opart,
                                                 const float* __restrict__ lpart,
                                                 unsigned short* __restrict__ ctxb) {
    int t = blockIdx.x * 256 + threadIdx.x;       // [0, 524288)
    int qq = t & 127, dh4 = (t >> 7) & 15, qt = (t >> 11) & 15, h = (t >> 15) & 7, b = t >> 18;
    int base = (qt << 5) | (h << 2) | (b << 1);   // flash bid with half=0
    float l = lpart[(size_t)base * 128 + qq] + lpart[(size_t)(base + 1) * 128 + qq];
    float inv = 1.f / l;
    ushort4v o;
    #pragma unroll
    for (int e = 0; e < 4; ++e) {
        int dh = dh4 * 4 + e;
        float v = (float)Opart[((size_t)base * 64 + dh) * 128 + qq]
                + (float)Opart[((size_t)(base + 1) * 64 + dh) * 128 + qq];
        o[e] = f2bf(v * inv);
    }
    *(ushort4v*)(ctxb + ((size_t)(b * L_) + qt * 128 + qq) * 512 + h * 64 + dh4 * 4) = o;
}

extern "C" void kernel_launch(void* const* d_in, const int* in_sizes, int n_in,
                              void* d_out, int out_size, void* d_ws, size_t ws_size,
                              hipStream_t stream) {
    (void)in_sizes; (void)n_in; (void)out_size; (void)ws_size;
    const float* x      = (const float*)d_in[0];
    const float* Wq     = (const float*)d_in[1];
    const float* Wk     = (const float*)d_in[2];
    const float* Wv     = (const float*)d_in[3];
    const float* Wb     = (const float*)d_in[4];
    const float* mixing = (const float*)d_in[5];
    const float* Wd     = (const float*)d_in[6];
    const float* bd     = (const float*)d_in[7];
    float* out = (float*)d_out;

    char* ws = (char*)d_ws;
    const size_t MiB = 1048576;
    unsigned short* xb     = (unsigned short*)(ws);                  // [0,4) MiB
    unsigned short* qb     = (unsigned short*)(ws + 4 * MiB);        // [4,8) bf16 q row-major
    unsigned char*  kpack8 = (unsigned char*)(ws + 8 * MiB);         // [8,10) fp8 K A-frags (x32)
    unsigned short* vfrag  = (unsigned short*)(ws + 10 * MiB);       // [10,14)
    unsigned short* ctxb   = (unsigned short*)(ws + 14 * MiB);       // [14,18)
    unsigned short* Wqb    = (unsigned short*)(ws + 18 * MiB);
    unsigned short* Wkb    = (unsigned short*)(ws + 18 * MiB + 512 * 1024);
    unsigned short* Wvb    = (unsigned short*)(ws + 19 * MiB);
    unsigned short* Wdb    = (unsigned short*)(ws + 19 * MiB + 512 * 1024);
    unsigned short* cbuf   = (unsigned short*)(ws + 20 * MiB);       // 64 KB (bf16)
    float* lpart           = (float*)(ws + 20 * MiB + 256 * 1024);   // 256 KB
    _Float16* Opart        = (_Float16*)(ws + 21 * MiB);             // [21,29) 8 MB

    cvt_cb<<<4096, 256, 0, stream>>>(x, Wq, Wk, Wv, Wd, Wb, xb, Wqb, Wkb, Wvb, Wdb, cbuf);
    gemm_qkv<<<dim3(32, 4, 3), 256, 0, stream>>>(xb, Wqb, Wkb, Wvb, qb, kpack8, vfrag);
    flash_attn<<<512, 256, 0, stream>>>(qb, kpack8, vfrag, cbuf, mixing, Opart, lpart);
    merge_ctx<<<2048, 256, 0, stream>>>(Opart, lpart, ctxb);
    gemm_out<<<dim3(32, 4), 256, 0, stream>>>(ctxb, Wdb, bd, out);
}

// Round 6
// 199.969 us; speedup vs baseline: 1.3547x; 1.0034x over previous
//
#include <hip/hip_runtime.h>

#define B_ 2
#define L_ 2048
#define D_ 512
#define H_ 8
#define S_ 2048

typedef __attribute__((ext_vector_type(8))) short short8;
typedef __attribute__((ext_vector_type(8))) unsigned short ushort8;
typedef __attribute__((ext_vector_type(4))) unsigned short ushort4v;
typedef __attribute__((ext_vector_type(4))) float f32x4;
typedef __attribute__((ext_vector_type(16))) float f32x16;
typedef __attribute__((ext_vector_type(4))) float float4v;

__device__ __forceinline__ unsigned short f2bf(float f) {
    unsigned u = __float_as_uint(f);
    u += 0x7FFF + ((u >> 16) & 1);   // RTNE
    return (unsigned short)(u >> 16);
}
__device__ __forceinline__ float bf2f(unsigned short s) {
    return __uint_as_float(((unsigned)s) << 16);
}
// f32 -> OCP e4m3 (RTNE, saturating)
__device__ __forceinline__ unsigned char f2fp8(float f) {
    return (unsigned char)(__builtin_amdgcn_cvt_pk_fp8_f32(f, f, 0, false) & 0xff);
}
// pack 8 f32 -> 8 e4m3 bytes in one i64 (byte j = v[j])
__device__ __forceinline__ long pack8fp8(const float* v) {
    int lo = __builtin_amdgcn_cvt_pk_fp8_f32(v[0], v[1], 0, false);
    lo = __builtin_amdgcn_cvt_pk_fp8_f32(v[2], v[3], lo, true);
    int hi = __builtin_amdgcn_cvt_pk_fp8_f32(v[4], v[5], 0, false);
    hi = __builtin_amdgcn_cvt_pk_fp8_f32(v[6], v[7], hi, true);
    union { int i[2]; long l; } u;
    u.i[0] = lo; u.i[1] = hi;
    return u.l;
}
// swap bits 2 and 3 (self-inverse) — K-row permutation making S^T C-regs = PV B-frag order
__device__ __forceinline__ int swap23(int x) {
    return (x & ~12) | ((x & 4) << 1) | ((x & 8) >> 1);
}
// async global->LDS, 16B per lane; LDS dest = uniform base + lane*16
__device__ __forceinline__ void async16(void* lds, const void* g) {
    __builtin_amdgcn_global_load_lds(
        (const __attribute__((address_space(1))) void*)(g),
        (__attribute__((address_space(3))) void*)(lds), 16, 0, 0);
}

// ---------------- fused: fp32->bf16 converts (blocks 0..3071) + content bias (blocks 3072..4095) ----------------
// cb PRE-SCALED by 1/8 and stored bf16: cb'[b,h,s] = dot(x,Wb)/8
__global__ __launch_bounds__(256) void cvt_cb(const float* __restrict__ x,
                                              const float* __restrict__ w0, const float* __restrict__ w1,
                                              const float* __restrict__ w2, const float* __restrict__ w3,
                                              const float* __restrict__ Wb,
                                              unsigned short* __restrict__ xb,
                                              unsigned short* __restrict__ d0, unsigned short* __restrict__ d1,
                                              unsigned short* __restrict__ d2, unsigned short* __restrict__ d3,
                                              unsigned short* __restrict__ cb) {
    if (blockIdx.x < 3072) {
        int i = blockIdx.x * 256 + threadIdx.x;   // [0, 786432)
        const float* s;
        unsigned short* d;
        int idx;
        if (i < 524288) { s = x; d = xb; idx = i; }
        else {
            int off = i - 524288;                  // [0, 262144): 4 weights x 65536 float4
            int wsel = off >> 16; idx = off & 65535;
            s = (wsel == 0) ? w0 : (wsel == 1) ? w1 : (wsel == 2) ? w2 : w3;
            d = (wsel == 0) ? d0 : (wsel == 1) ? d1 : (wsel == 2) ? d2 : d3;
        }
        float4v v = *(const float4v*)(s + (size_t)idx * 4);
        ushort4v o;
        o[0] = f2bf(v[0]); o[1] = f2bf(v[1]); o[2] = f2bf(v[2]); o[3] = f2bf(v[3]);
        *(ushort4v*)(d + (size_t)idx * 4) = o;
    } else {
        const int tid = threadIdx.x, w = tid >> 6, lane = tid & 63;
        const int row = (blockIdx.x - 3072) * 4 + w;   // [0, 4096)
        const int h = lane >> 3, seg = lane & 7;
        const float* xp = x + (size_t)row * 512 + seg * 64;
        const float* wp = Wb + (size_t)h * 512 + seg * 64;
        float acc = 0.f;
        #pragma unroll
        for (int j = 0; j < 16; ++j) {
            float4v xv = *(const float4v*)(xp + j * 4);
            float4v wv = *(const float4v*)(wp + j * 4);
            acc += xv[0] * wv[0] + xv[1] * wv[1] + xv[2] * wv[2] + xv[3] * wv[3];
        }
        acc += __shfl_xor(acc, 1);
        acc += __shfl_xor(acc, 2);
        acc += __shfl_xor(acc, 4);
        if (seg == 0) {
            int b = row >> 11, s = row & 2047;
            cb[((size_t)(b * H_ + h)) * S_ + s] = f2bf(acc * 0.125f);
        }
    }
}

// ---------------- 128x128-tile GEMM core: 4 waves in 2x2, each 64x64 quadrant ----------------
__device__ __forceinline__ void gemm128_core(const unsigned short* __restrict__ Ap,
                                             const unsigned short* __restrict__ Bp,
                                             short* sA, short* sB, int tid, f32x4 c[4][4]) {
    const int w = tid >> 6, lane = tid & 63, quad = lane >> 4, l15 = lane & 15;
    const int wm = (w >> 1) * 64, wn = (w & 1) * 64;
    for (int kc = 0; kc < 8; ++kc) {
        __syncthreads();
        #pragma unroll
        for (int j = 0; j < 4; ++j) {
            int i = tid + j * 256;          // 1024 slots = 128 rows x 64 cols / 8
            int row = i >> 3, seg = i & 7;
            *(ushort8*)&sA[row * 72 + seg * 8] = *(const ushort8*)(Ap + (size_t)row * 512 + kc * 64 + seg * 8);
            *(ushort8*)&sB[row * 72 + seg * 8] = *(const ushort8*)(Bp + (size_t)row * 512 + kc * 64 + seg * 8);
        }
        __syncthreads();
        #pragma unroll
        for (int ks = 0; ks < 2; ++ks) {
            short8 a[4], b[4];
            #pragma unroll
            for (int ii = 0; ii < 4; ++ii)
                a[ii] = *(const short8*)&sA[(wm + ii * 16 + l15) * 72 + ks * 32 + quad * 8];
            #pragma unroll
            for (int jj = 0; jj < 4; ++jj)
                b[jj] = *(const short8*)&sB[(wn + jj * 16 + l15) * 72 + ks * 32 + quad * 8];
            #pragma unroll
            for (int ii = 0; ii < 4; ++ii)
                #pragma unroll
                for (int jj = 0; jj < 4; ++jj)
                    c[ii][jj] = __builtin_amdgcn_mfma_f32_16x16x32_bf16(a[ii], b[jj], c[ii][jj], 0, 0, 0);
        }
    }
}

// ---------------- q,k,v projections (128x128 tiles) ----------------
// q: row-major bf16 (flash folds mixing + quantizes per-head in-register).
// K: fp8 e4m3 (x32, NO mixing) A-frag pair-packed, rows sigma-permuted:
//    byte = ((b*64 + (s>>5))*16 + (d>>5))*1024 + (((d>>3)&1)*32 + swap23(s&31))*16 + ((d>>4)&1)*8 + (d&7)
// V: frag-major vfrag[(b,h,T,f)][lane*8] — flash reads one dwordx4/lane.
__global__ __launch_bounds__(256) void gemm_qkv(const unsigned short* __restrict__ xb,
                                                const unsigned short* __restrict__ Wqb,
                                                const unsigned short* __restrict__ Wkb,
                                                const unsigned short* __restrict__ Wvb,
                                                unsigned short* __restrict__ qb,
                                                unsigned char* __restrict__ kpack8,
                                                unsigned short* __restrict__ vfrag) {
    __shared__ short sA[128 * 72];
    __shared__ short sB[128 * 72];
    const int m0 = blockIdx.x * 128, n0 = blockIdx.y * 128, z = blockIdx.z;
    const unsigned short* Bsel = (z == 0) ? Wqb : ((z == 1) ? Wkb : Wvb);
    f32x4 c[4][4];
    #pragma unroll
    for (int ii = 0; ii < 4; ++ii)
        #pragma unroll
        for (int jj = 0; jj < 4; ++jj) { f32x4 zv = {0.f, 0.f, 0.f, 0.f}; c[ii][jj] = zv; }
    gemm128_core(xb + (size_t)m0 * 512, Bsel + (size_t)n0 * 512, sA, sB, threadIdx.x, c);
    const int tid = threadIdx.x, w = tid >> 6, lane = tid & 63, quad = lane >> 4, l15 = lane & 15;
    const int wm = (w >> 1) * 64, wn = (w & 1) * 64;
    #pragma unroll
    for (int ii = 0; ii < 4; ++ii) {
        const int mb = m0 + wm + ii * 16 + quad * 4;
        const int bb = mb >> 11;
        if (z == 0) {
            #pragma unroll
            for (int jj = 0; jj < 4; ++jj) {
                int ncol = n0 + wn + jj * 16 + l15;
                #pragma unroll
                for (int r = 0; r < 4; ++r)
                    qb[(size_t)(mb + r) * 512 + ncol] = f2bf(c[ii][jj][r]);
            }
        } else if (z == 1) {
            #pragma unroll
            for (int jj = 0; jj < 4; ++jj) {
                int d = n0 + wn + jj * 16 + l15;
                int pair = d >> 5, fh = (d >> 4) & 1, hid = (d >> 3) & 1, jq = d & 7;
                #pragma unroll
                for (int r = 0; r < 4; ++r) {
                    int s = (mb + r) & 2047;
                    int t = s >> 5, rr = swap23(s & 31);
                    kpack8[(((size_t)(bb * 64 + t) * 16 + pair) << 10)
                           + (hid * 32 + rr) * 16 + fh * 8 + jq] = f2fp8(c[ii][jj][r] * 32.f);
                }
            }
        } else {
            const int hh = (n0 + wn) >> 6;
            const int s = mb & 2047;              // s..s+3 along r, s%4==0
            #pragma unroll
            for (int jj = 0; jj < 4; ++jj) {
                int dh = jj * 16 + l15;
                ushort4v o;
                o[0] = f2bf(c[ii][jj][0]); o[1] = f2bf(c[ii][jj][1]);
                o[2] = f2bf(c[ii][jj][2]); o[3] = f2bf(c[ii][jj][3]);
                size_t blk = ((size_t)(bb * H_ + hh) * 64 + (s >> 5)) * 4
                           + ((dh >> 5) * 2 + ((s >> 4) & 1));
                *(ushort4v*)(vfrag + blk * 512 + (dh & 31) * 8 + ((s >> 3) & 1) * 256 + (s & 7)) = o;
            }
        }
    }
}

// ---------------- output projection (128x128 tiles, fp32 out + bias) ----------------
__global__ __launch_bounds__(256) void gemm_out(const unsigned short* __restrict__ ctxb,
                                                const unsigned short* __restrict__ Wdb,
                                                const float* __restrict__ bd,
                                                float* __restrict__ out) {
    __shared__ short sA[128 * 72];
    __shared__ short sB[128 * 72];
    const int m0 = blockIdx.x * 128, n0 = blockIdx.y * 128;
    f32x4 c[4][4];
    #pragma unroll
    for (int ii = 0; ii < 4; ++ii)
        #pragma unroll
        for (int jj = 0; jj < 4; ++jj) { f32x4 zv = {0.f, 0.f, 0.f, 0.f}; c[ii][jj] = zv; }
    gemm128_core(ctxb + (size_t)m0 * 512, Wdb + (size_t)n0 * 512, sA, sB, threadIdx.x, c);
    const int tid = threadIdx.x, w = tid >> 6, lane = tid & 63, quad = lane >> 4, l15 = lane & 15;
    const int wm = (w >> 1) * 64, wn = (w & 1) * 64;
    #pragma unroll
    for (int ii = 0; ii < 4; ++ii) {
        const int mb = m0 + wm + ii * 16 + quad * 4;
        #pragma unroll
        for (int jj = 0; jj < 4; ++jj) {
            int ncol = n0 + wn + jj * 16 + l15;
            float bias = bd[ncol];
            #pragma unroll
            for (int r = 0; r < 4; ++r)
                out[(size_t)(mb + r) * 512 + ncol] = c[ii][jj][r] + bias;
        }
    }
}

// ---------------- flash attention v15: v14 + T15 softmax-deferral (att[2] double-pipeline) ----------------
// softmax+PV of tile t-1 runs in the MFMA shadow of tile t's first QK chunk: per tile E-phase is
// {vmcnt(12); barrier; stageK(2t+3); 16 QK MFMAs (bank t&1); vmcnt(4); softmax_pv(bank ~t&1); ldV(t); ldCB(t)}.
// S-accumulators double-banked (manual 2x unroll -> static banks, rule #20); av/cbr single-buffered
// (reloaded after consumption). Hand-traced FIFO (counted, never drains K prefetch):
//   steady E: vmcnt(12) [drain K(2t)], then vmcnt(4) [drain V(t-1)+cb(t-1), leaves K(2t+2),K(2t+3)].
//   peels: t=0 E vmcnt(4), O vmcnt(12); t=31: E vmcnt(10)/vmcnt(2), O vmcnt(8)/vmcnt(0).
// Logit scale: q*16, k*32, /8 head -> accs/4096.
__global__ __launch_bounds__(256, 2) void flash_attn(const unsigned short* __restrict__ qb,
                                                     const unsigned char* __restrict__ kpack8,
                                                     const unsigned short* __restrict__ vfrag,
                                                     const unsigned short* __restrict__ cb_all,
                                                     const float* __restrict__ mixing,
                                                     _Float16* __restrict__ Opart,
                                                     float* __restrict__ lpart) {
    __shared__ char sK[4][8192];     // 4 x 8 KB fp8 K-chunk buffers (8 frag-pairs x 1024 B each)
    const int bid = blockIdx.x;
    const int half = bid & 1, b = (bid >> 1) & 1, h = (bid >> 2) & 7, qt = bid >> 5;
    const int tid = threadIdx.x, w = tid >> 6, lane = tid & 63;
    const int l31 = lane & 31, hi = lane >> 5;
    const int q0 = qt * 128 + w * 32;
    const unsigned short* vfb = vfrag + ((size_t)(b * H_ + h) * 64 + half * 32) * 2048;
    const unsigned short* cbq = cb_all + (size_t)(b * H_ + h) * S_ + half * 1024;
    const float* mixh = mixing + h * D_;

    // ---- Q: bf16 rows -> x mixing (f32) -> fp8 B-frags in regs (frag i: d = i*16 + hi*8 + j) ----
    long qq[32];
    {
        const unsigned short* qrow = qb + ((size_t)(b * L_) + q0 + l31) * D_ + hi * 8;
        #pragma unroll
        for (int i = 0; i < 32; ++i) {
            ushort8 qv = *(const ushort8*)(qrow + i * 16);
            float4v ma = *(const float4v*)(mixh + i * 16 + hi * 8);
            float4v mb = *(const float4v*)(mixh + i * 16 + hi * 8 + 4);
            float v[8];
            v[0] = bf2f(qv[0]) * ma[0] * 16.f;
            v[1] = bf2f(qv[1]) * ma[1] * 16.f;
            v[2] = bf2f(qv[2]) * ma[2] * 16.f;
            v[3] = bf2f(qv[3]) * ma[3] * 16.f;
            v[4] = bf2f(qv[4]) * mb[0] * 16.f;
            v[5] = bf2f(qv[5]) * mb[1] * 16.f;
            v[6] = bf2f(qv[6]) * mb[2] * 16.f;
            v[7] = bf2f(qv[7]) * mb[3] * 16.f;
            qq[i] = pack8fp8(v);
        }
    }
    // Drain Q/mixing loads so the hand-counted vmcnt FIFO below starts clean.
    asm volatile("s_waitcnt vmcnt(0)" ::: "memory");

    f32x16 acco0, acco1;
    #pragma unroll
    for (int i = 0; i < 16; ++i) { acco0[i] = 0.f; acco1[i] = 0.f; }
    float lsum = 0.f;
    f32x16 aA0, aB0, aA1, aB1;           // S accumulators, 2 banks (even/odd tile)
    short8 av00, av01, av10, av11;       // V frags (bf16) in regs, single-buffered
    ushort8 cbr0, cbr1, cbr2, cbr3;      // cb tile (bf16) in regs, single-buffered

    auto stageK = [&](int p) {
        const char* src = (const char*)kpack8 + (((size_t)(b * 64 + half * 32)) << 14) + (size_t)p * 8192;
        char* dst = &sK[p & 3][0];
        #pragma unroll
        for (int ii = 0; ii < 2; ++ii)
            async16(dst + w * 1024 + ii * 4096, src + w * 1024 + ii * 4096 + (size_t)lane * 16);
    };
    auto ldV = [&](int t) {
        const unsigned short* vp = vfb + (size_t)t * 2048 + lane * 8;
        av00 = *(const short8*)(vp);
        av01 = *(const short8*)(vp + 512);
        av10 = *(const short8*)(vp + 1024);
        av11 = *(const short8*)(vp + 1536);
        asm volatile("" ::: "memory");   // pin the 4 V loads at this FIFO position
    };
    auto ldCB = [&](int t) {
        const unsigned short* cp = cbq + t * 32;
        cbr0 = *(const ushort8*)(cp);
        cbr1 = *(const ushort8*)(cp + 8);
        cbr2 = *(const ushort8*)(cp + 16);
        cbr3 = *(const ushort8*)(cp + 24);
        asm volatile("" ::: "memory");   // pin the 4 cb loads at this FIFO position
    };
    auto qk_chunk = [&](const char* buf, int qbase, f32x16& A, f32x16& B) {
        __builtin_amdgcn_s_setprio(1);
        #pragma unroll
        for (int p = 0; p < 8; ++p) {
            long a0, a1;
            {
                const long* ap = (const long*)&buf[p * 1024 + lane * 16];
                a0 = ap[0];
                a1 = ap[1];
            }
            A = __builtin_amdgcn_mfma_f32_32x32x16_fp8_fp8(a0, qq[qbase + 2 * p], A, 0, 0, 0);
            B = __builtin_amdgcn_mfma_f32_32x32x16_fp8_fp8(a1, qq[qbase + 2 * p + 1], B, 0, 0, 0);
        }
        __builtin_amdgcn_s_setprio(0);
    };
    // softmax + PV for the tile whose S sits in (A,B); consumes current av/cbr.
    auto softmax_pv = [&](const f32x16& A, const f32x16& B) {
        float p[16];
        #pragma unroll
        for (int R = 0; R < 16; ++R) {
            const int cr = (R & 3) + 8 * (R >> 2);
            const int il = cr - 4 * ((R >> 2) & 1);    // in [0..7] u [16..23]
            const int ih = il + 8;                      // in [8..15] u [24..31]
            unsigned short ca = (il < 8)  ? cbr0[il & 7] : cbr2[il & 7];
            unsigned short cbb = (ih < 16) ? cbr1[ih & 7] : cbr3[ih & 7];
            float cbv = bf2f(hi ? cbb : ca);
            float pe = __expf((A[R] + B[R]) * (1.0f / 4096.0f) + cbv);
            p[R] = pe;
            lsum += pe;
        }
        union { unsigned int u[4]; short8 s8; } P0, P1;
        #pragma unroll
        for (int j = 0; j < 4; ++j) {
            P0.u[j] = __builtin_amdgcn_perm(__float_as_uint(p[2 * j + 1]) + 0x8000u,
                                            __float_as_uint(p[2 * j]) + 0x8000u, 0x07060302u);
            P1.u[j] = __builtin_amdgcn_perm(__float_as_uint(p[8 + 2 * j + 1]) + 0x8000u,
                                            __float_as_uint(p[8 + 2 * j]) + 0x8000u, 0x07060302u);
        }
        __builtin_amdgcn_s_setprio(1);
        acco0 = __builtin_amdgcn_mfma_f32_32x32x16_bf16(av00, P0.s8, acco0, 0, 0, 0);
        acco0 = __builtin_amdgcn_mfma_f32_32x32x16_bf16(av01, P1.s8, acco0, 0, 0, 0);
        acco1 = __builtin_amdgcn_mfma_f32_32x32x16_bf16(av10, P0.s8, acco1, 0, 0, 0);
        acco1 = __builtin_amdgcn_mfma_f32_32x32x16_bf16(av11, P1.s8, acco1, 0, 0, 0);
        __builtin_amdgcn_s_setprio(0);
    };
    auto zero16 = [](f32x16& v) {
        #pragma unroll
        for (int i = 0; i < 16; ++i) v[i] = 0.f;
    };

    // ---- prologue: 3 K-chunks in flight (6 loads) ----
    stageK(0); stageK(1); stageK(2);

    // ---- t = 0 (bank0; no deferred softmax yet) ----
    zero16(aA0); zero16(aB0);
    asm volatile("s_waitcnt vmcnt(4)" ::: "memory");    // drain K0
    __builtin_amdgcn_s_barrier();
    stageK(3);
    qk_chunk(&sK[0][0], 0, aA0, aB0);
    ldV(0); ldCB(0);
    asm volatile("s_waitcnt vmcnt(12)" ::: "memory");   // drain K1 (queue: K1,K2,K3,V0,cb0)
    __builtin_amdgcn_s_barrier();
    stageK(4);
    qk_chunk(&sK[1][0], 16, aA0, aB0);

    // ---- main loop: tile pairs (odd tile -> bank1, even tile -> bank0), t = 1..30 ----
    #define E_TILE(T, CA, CB, PA, PB)                                            \
        zero16(CA); zero16(CB);                                                  \
        asm volatile("s_waitcnt vmcnt(12)" ::: "memory");  /* drain K(2T) */     \
        __builtin_amdgcn_s_barrier();                                            \
        stageK(2 * (T) + 3);                                                     \
        qk_chunk(&sK[((T) & 1) << 1][0], 0, CA, CB);                             \
        asm volatile("s_waitcnt vmcnt(4)" ::: "memory");   /* drain V,cb(T-1) */ \
        softmax_pv(PA, PB);                                                      \
        ldV(T); ldCB(T);
    #define O_TILE(T, CA, CB)                                                    \
        __builtin_amdgcn_s_barrier();                                            \
        if ((T) < 30) stageK(2 * (T) + 4);                                       \
        qk_chunk(&sK[(((T) & 1) << 1) | 1][0], 16, CA, CB);

    for (int tt = 1; tt < 30; tt += 2) {
        E_TILE(tt, aA1, aB1, aA0, aB0);
        O_TILE(tt, aA1, aB1);
        E_TILE(tt + 1, aA0, aB0, aA1, aB1);
        O_TILE(tt + 1, aA0, aB0);
    }
    #undef E_TILE
    #undef O_TILE

    // ---- t = 31 (bank1; deferred softmax of t=30 in bank0) ----
    {
        zero16(aA1); zero16(aB1);
        asm volatile("s_waitcnt vmcnt(10)" ::: "memory");   // drain K62 (queue: K62,K63,V30,cb30)
        __builtin_amdgcn_s_barrier();
        qk_chunk(&sK[2][0], 0, aA1, aB1);
        asm volatile("s_waitcnt vmcnt(2)" ::: "memory");    // drain V30,cb30 (leaves K63)
        softmax_pv(aA0, aB0);
        ldV(31); ldCB(31);
        asm volatile("s_waitcnt vmcnt(8)" ::: "memory");    // drain K63 (leaves V31,cb31)
        __builtin_amdgcn_s_barrier();
        qk_chunk(&sK[3][0], 16, aA1, aB1);
        asm volatile("s_waitcnt vmcnt(0)" ::: "memory");    // drain V31,cb31
        softmax_pv(aA1, aB1);
    }

    // ---- epilogue: lsum merge, fp16 O^T partials ----
    lsum += __shfl_xor(lsum, 32);
    if (hi == 0) lpart[(size_t)bid * 128 + w * 32 + l31] = lsum;
    #pragma unroll
    for (int R = 0; R < 16; ++R) {
        int dh = (R & 3) + 8 * (R >> 2) + 4 * hi;
        Opart[((size_t)bid * 64 + dh) * 128 + w * 32 + l31] = (_Float16)acco0[R];
        Opart[((size_t)bid * 64 + 32 + dh) * 128 + w * 32 + l31] = (_Float16)acco1[R];
    }
}

// ---------------- merge 2 split-S partials -> ctx (bf16) ----------------
__global__ __launch_bounds__(256) void merge_ctx(const _Float16* __restrict__ Opart,
                                                 const float* __restrict__ lpart,
                                                 unsigned short* __restrict__ ctxb) {
    int t = blockIdx.x * 256 + threadIdx.x;       // [0, 524288)
    int qq = t & 127, dh4 = (t >> 7) & 15, qt = (t >> 11) & 15, h = (t >> 15) & 7, b = t >> 18;
    int base = (qt << 5) | (h << 2) | (b << 1);   // flash bid with half=0
    float l = lpart[(size_t)base * 128 + qq] + lpart[(size_t)(base + 1) * 128 + qq];
    float inv = 1.f / l;
    ushort4v o;
    #pragma unroll
    for (int e = 0; e < 4; ++e) {
        int dh = dh4 * 4 + e;
        float v = (float)Opart[((size_t)base * 64 + dh) * 128 + qq]
                + (float)Opart[((size_t)(base + 1) * 64 + dh) * 128 + qq];
        o[e] = f2bf(v * inv);
    }
    *(ushort4v*)(ctxb + ((size_t)(b * L_) + qt * 128 + qq) * 512 + h * 64 + dh4 * 4) = o;
}

extern "C" void kernel_launch(void* const* d_in, const int* in_sizes, int n_in,
                              void* d_out, int out_size, void* d_ws, size_t ws_size,
                              hipStream_t stream) {
    (void)in_sizes; (void)n_in; (void)out_size; (void)ws_size;
    const float* x      = (const float*)d_in[0];
    const float* Wq     = (const float*)d_in[1];
    const float* Wk     = (const float*)d_in[2];
    const float* Wv     = (const float*)d_in[3];
    const float* Wb     = (const float*)d_in[4];
    const float* mixing = (const float*)d_in[5];
    const float* Wd     = (const float*)d_in[6];
    const float* bd     = (const float*)d_in[7];
    float* out = (float*)d_out;

    char* ws = (char*)d_ws;
    const size_t MiB = 1048576;
    unsigned short* xb     = (unsigned short*)(ws);                  // [0,4) MiB
    unsigned short* qb     = (unsigned short*)(ws + 4 * MiB);        // [4,8) bf16 q row-major
    unsigned char*  kpack8 = (unsigned char*)(ws + 8 * MiB);         // [8,10) fp8 K A-frags (x32)
    unsigned short* vfrag  = (unsigned short*)(ws + 10 * MiB);       // [10,14)
    unsigned short* ctxb   = (unsigned short*)(ws + 14 * MiB);       // [14,18)
    unsigned short* Wqb    = (unsigned short*)(ws + 18 * MiB);
    unsigned short* Wkb    = (unsigned short*)(ws + 18 * MiB + 512 * 1024);
    unsigned short* Wvb    = (unsigned short*)(ws + 19 * MiB);
    unsigned short* Wdb    = (unsigned short*)(ws + 19 * MiB + 512 * 1024);
    unsigned short* cbuf   = (unsigned short*)(ws + 20 * MiB);       // 64 KB (bf16)
    float* lpart           = (float*)(ws + 20 * MiB + 256 * 1024);   // 256 KB
    _Float16* Opart        = (_Float16*)(ws + 21 * MiB);             // [21,29) 8 MB

    cvt_cb<<<4096, 256, 0, stream>>>(x, Wq, Wk, Wv, Wd, Wb, xb, Wqb, Wkb, Wvb, Wdb, cbuf);
    gemm_qkv<<<dim3(32, 4, 3), 256, 0, stream>>>(xb, Wqb, Wkb, Wvb, qb, kpack8, vfrag);
    flash_attn<<<512, 256, 0, stream>>>(qb, kpack8, vfrag, cbuf, mixing, Opart, lpart);
    merge_ctx<<<2048, 256, 0, stream>>>(Opart, lpart, ctxb);
    gemm_out<<<dim3(32, 4), 256, 0, stream>>>(ctxb, Wdb, bd, out);
}